// Round 12
// baseline (315.815 us; speedup 1.0000x reference)
//
#include <hip/hip_runtime.h>

// GraphTransformerLayer — MI355X
// r6=574 r7=418 r8=401 r9=384 r10=350 r11=308 us.
// r11 profile: agg=52us top; prefetch-1 insufficient (2 loads in flight vs
// ~400cy gather latency). r12: 4-deep double-buffered prefetch (8 loads in
// flight), fp32 residual chain (absmax margin), hist merged into prep.
#define NN 20000
#define EE 160000
#define DD 128
#define GHC 512
#define INV_SQRT_HC 0.08838834764831845f  // 1/sqrt(128)

typedef __attribute__((ext_vector_type(8))) short short8;
typedef __attribute__((ext_vector_type(4))) short short4v;
typedef __attribute__((ext_vector_type(4))) float float4v;
typedef __attribute__((ext_vector_type(4))) unsigned uint4v;

__device__ inline float bf2f(unsigned short u) {
    union { unsigned u; float f; } x; x.u = ((unsigned)u) << 16; return x.f;
}
__device__ inline unsigned short f2bf(float f) {
    union { float f; unsigned u; } x; x.f = f;
    unsigned u = x.u;
    unsigned r = (u + 0x7fffu + ((u >> 16) & 1u)) >> 16;
    return (unsigned short)r;
}

// ---------------------------------------------------------------------------
// prep: [0,1024) convert x+te -> bf16 | [1024,1600) weight pack |
//       [1600,1664) wcomb | [1664,2289) dst histogram.  One dispatch.
// counts must be pre-zeroed (memset before this dispatch).
// ---------------------------------------------------------------------------
struct WPack { const void* in[18]; };
__device__ __constant__ const int WSZ[18] = {
    65536, 65536, 65536, 512, 512, 512,
    16384, 128, 65536, 512, 65536, 128,
    128, 128, 128, 128, 128, 128 };

__global__ void prep_kernel(const float* __restrict__ x, const float* __restrict__ te,
                            unsigned short* __restrict__ xcout, WPack p,
                            unsigned short* __restrict__ wcout,
                            const float* __restrict__ wv, const float* __restrict__ bv,
                            const float* __restrict__ wo, const float* __restrict__ bo,
                            unsigned short* __restrict__ wcomb,
                            unsigned short* __restrict__ bcomb,
                            const int* __restrict__ e_dst, int* __restrict__ counts)
{
    const int b = blockIdx.x;
    const int tid = threadIdx.x;
    if (b < 1024) {
        const long n4half = (long)NN * DD / 4;
        short4v* out4 = reinterpret_cast<short4v*>(xcout);
        long i = (long)b * 256 + tid;
        const long stride = 1024L * 256;
        const long tot = 2 * n4half;
        for (; i < tot; i += stride) {
            const float4v* src = (i < n4half)
                ? reinterpret_cast<const float4v*>(x)
                : reinterpret_cast<const float4v*>(te) - n4half;
            float4v v = src[i];
            short4v o;
            o[0] = (short)f2bf(v[0]); o[1] = (short)f2bf(v[1]);
            o[2] = (short)f2bf(v[2]); o[3] = (short)f2bf(v[3]);
            out4[i] = o;
        }
    } else if (b < 1600) {
        const int seg = (b - 1024) >> 5;
        const int rep = (b - 1024) & 31;
        int off = 0;
#pragma unroll
        for (int s = 0; s < 18; ++s) if (s < seg) off += WSZ[s];
        const int n = WSZ[seg];
        const float* q = (const float*)p.in[seg];
        for (int i = rep * 256 + tid; i < n; i += 32 * 256)
            wcout[off + i] = f2bf(q[i]);
    } else if (b < 1664) {
        int e = (b - 1600) * 256 + tid;   // 16384 total
        int i = e >> 7, kk = e & 127;
        float s = 0.f;
        for (int j = 0; j < 128; ++j)
            s += wo[i * 128 + j] * wv[j * 128 + kk];
        wcomb[e] = f2bf(s);
        if (b == 1600 && tid < 128) {
            float t = 0.f;
            for (int j = 0; j < 128; ++j) t += wo[tid * 128 + j] * bv[j];
            bcomb[tid] = f2bf(t + bo[tid]);
        }
    } else {
        int e = (b - 1664) * 256 + tid;
        if (e < EE) {
            int d = e_dst[e];
            if (d >= 0 && d < NN) atomicAdd(&counts[d], 1);
        }
    }
}

// ---------------------------------------------------------------------------
// GEMM v3 (K=128, 128 cols/block): W slice (32KB) staged in LDS frag-major.
// Output remap: cols >= split go to out2 (stride Nout2) — splits q / kv.
// ---------------------------------------------------------------------------
__global__ __launch_bounds__(256) void gemm3_kernel(
    const unsigned short* __restrict__ A, const unsigned short* __restrict__ W,
    const unsigned short* __restrict__ bias, unsigned short* __restrict__ out,
    unsigned short* __restrict__ out2, int M, int Nout, int Nout2, int split,
    int relu)
{
    __shared__ short8 wslab[2048];                                     // 32 KB
    __shared__ __attribute__((aligned(16))) unsigned stile[4][16][36]; // 9 KB
    const int tid  = threadIdx.x;
    const int lane = tid & 63;
    const int wid  = tid >> 6;
    const int quad = lane >> 4;
    const int l15  = lane & 15;
    const int rowbase  = blockIdx.x * 64 + wid * 16;
    const int colbase0 = blockIdx.y * 128;

    unsigned short* ob; int nout, cb0;
    if (colbase0 < split) { ob = out;  nout = Nout;  cb0 = colbase0; }
    else                  { ob = out2; nout = Nout2; cb0 = colbase0 - split; }

    const short8* A8 = reinterpret_cast<const short8*>(A);
    const short8* W8 = reinterpret_cast<const short8*>(W);

#pragma unroll
    for (int rep = 0; rep < 8; ++rep) {
        int f   = rep * 256 + tid;            // 0..2047
        int fl  = f & 63;
        int fi  = (f >> 6) & 3;
        int ft  = (f >> 8) & 3;
        int ftt = f >> 10;
        int wrow = colbase0 + ftt * 64 + 16 * ft + (fl & 15);
        wslab[f] = W8[(size_t)wrow * 16 + fi * 4 + (fl >> 4)];
    }

    int arow = rowbase + l15;
    if (arow >= M) arow = M - 1;
    short8 a4[4];
#pragma unroll
    for (int i = 0; i < 4; ++i) a4[i] = A8[(size_t)arow * 16 + i * 4 + quad];

    __syncthreads();

#pragma unroll
    for (int tt = 0; tt < 2; ++tt) {
        const int colbase = colbase0 + tt * 64;
        float4v acc[4];
#pragma unroll
        for (int t = 0; t < 4; ++t) acc[t] = (float4v){0.f, 0.f, 0.f, 0.f};

#pragma unroll
        for (int i = 0; i < 4; ++i) {
#pragma unroll
            for (int t = 0; t < 4; ++t) {
                short8 b = wslab[((tt * 4 + t) * 4 + i) * 64 + lane];
                acc[t] = __builtin_amdgcn_mfma_f32_16x16x32_bf16(a4[i], b, acc[t], 0, 0, 0);
            }
        }

#pragma unroll
        for (int t = 0; t < 4; ++t) {
            float bv = bf2f(bias[colbase + 16 * t + l15]);
#pragma unroll
            for (int r = 0; r < 4; ++r) {
                float vv = acc[t][r] + bv;
                if (relu) vv = fmaxf(vv, 0.f);
                float ov = __shfl_xor(vv, 1, 64);
                if ((l15 & 1) == 0)
                    stile[wid][quad * 4 + r][8 * t + (l15 >> 1)] =
                        (unsigned)f2bf(vv) | ((unsigned)f2bf(ov) << 16);
            }
        }
        const int rr0 = lane >> 3;
        const int cd  = (lane & 7) * 4;
#pragma unroll
        for (int it = 0; it < 2; ++it) {
            int rr = rr0 + it * 8;
            int grow = rowbase + rr;
            if (grow < M) {
                uint4v v = *reinterpret_cast<const uint4v*>(&stile[wid][rr][cd]);
                *reinterpret_cast<uint4v*>(&ob[(size_t)grow * nout + cb0 + tt * 64 + cd * 2]) = v;
            }
        }
    }
}

// ---------------------------------------------------------------------------
// GEMM + residual + LN fused, W-in-LDS chunked (Nout=128; K multiple of 128).
// outf(f32) = LN(residf_f32 + (A@W^T + bias) [+ c_f32]) * g + beta;
// optional outb = bf16 copy (feeds next MFMA stage).
// ---------------------------------------------------------------------------
__global__ __launch_bounds__(256) void gemm_ln2_kernel(
    const unsigned short* __restrict__ A, const unsigned short* __restrict__ W,
    const unsigned short* __restrict__ bias,
    const float* __restrict__ residf, const float* __restrict__ c,
    const unsigned short* __restrict__ g, const unsigned short* __restrict__ beta,
    float* __restrict__ outf, unsigned short* __restrict__ outb, int M, int K)
{
    __shared__ short8 wslab[2048];                // 32 KB
    __shared__ unsigned short stile[4][16][136];
    const int tid  = threadIdx.x;
    const int lane = tid & 63;
    const int wid  = tid >> 6;
    const int quad = lane >> 4;
    const int l15  = lane & 15;
    const int rowbase = blockIdx.x * 64 + wid * 16;

    int arow = rowbase + l15;
    if (arow >= M) arow = M - 1;

    const short8* A8 = reinterpret_cast<const short8*>(A);
    const short8* W8 = reinterpret_cast<const short8*>(W);
    const int k8 = K >> 3;
    const int kchunks = K >> 7;

    float4v acc[2][4];
#pragma unroll
    for (int tt = 0; tt < 2; ++tt)
#pragma unroll
        for (int t = 0; t < 4; ++t) acc[tt][t] = (float4v){0.f, 0.f, 0.f, 0.f};

    for (int cc = 0; cc < kchunks; ++cc) {
        if (cc > 0) __syncthreads();
#pragma unroll
        for (int rep = 0; rep < 8; ++rep) {
            int f   = rep * 256 + tid;
            int fl  = f & 63;
            int fi  = (f >> 6) & 3;
            int ft  = (f >> 8) & 3;
            int ftt = f >> 10;
            int wrow = ftt * 64 + 16 * ft + (fl & 15);
            wslab[f] = W8[(size_t)wrow * k8 + cc * 16 + fi * 4 + (fl >> 4)];
        }
        short8 a4[4];
#pragma unroll
        for (int i = 0; i < 4; ++i) a4[i] = A8[(size_t)arow * k8 + cc * 16 + i * 4 + quad];
        __syncthreads();
#pragma unroll
        for (int tt = 0; tt < 2; ++tt)
#pragma unroll
            for (int i = 0; i < 4; ++i)
#pragma unroll
                for (int t = 0; t < 4; ++t) {
                    short8 b = wslab[((tt * 4 + t) * 4 + i) * 64 + lane];
                    acc[tt][t] = __builtin_amdgcn_mfma_f32_16x16x32_bf16(a4[i], b, acc[tt][t], 0, 0, 0);
                }
    }

#pragma unroll
    for (int tt = 0; tt < 2; ++tt)
#pragma unroll
        for (int t = 0; t < 4; ++t) {
            float bv = bf2f(bias[tt * 64 + 16 * t + l15]);
#pragma unroll
            for (int r = 0; r < 4; ++r)
                stile[wid][quad * 4 + r][tt * 64 + 16 * t + l15] = f2bf(acc[tt][t][r] + bv);
        }

    // LN epilogue: 4 lanes/row, 32 ch/lane (wave-private; lgkmcnt orders)
    const int r  = lane >> 2;
    const int p  = lane & 3;
    const int grow = rowbase + r;
    const int gr = (grow < M) ? grow : M - 1;

    float v[32];
    const short8* st8 = reinterpret_cast<const short8*>(&stile[wid][r][p * 32]);
#pragma unroll
    for (int q = 0; q < 4; ++q) {
        short8 sb = st8[q];
#pragma unroll
        for (int j = 0; j < 8; ++j) v[q * 8 + j] = bf2f((unsigned short)sb[j]);
    }
    const float4v* r4 = reinterpret_cast<const float4v*>(&residf[(size_t)gr * 128 + p * 32]);
#pragma unroll
    for (int q = 0; q < 8; ++q) {
        float4v rv = r4[q];
#pragma unroll
        for (int j = 0; j < 4; ++j) v[q * 4 + j] += rv[j];
    }
    if (c) {
        const float4v* c4 = reinterpret_cast<const float4v*>(&c[(size_t)gr * 128 + p * 32]);
#pragma unroll
        for (int q = 0; q < 8; ++q) {
            float4v cv = c4[q];
#pragma unroll
            for (int j = 0; j < 4; ++j) v[q * 4 + j] += cv[j];
        }
    }
    float s = 0.f, sq = 0.f;
#pragma unroll
    for (int i = 0; i < 32; ++i) { s += v[i]; sq += v[i] * v[i]; }
    s  += __shfl_xor(s, 1, 64);  s  += __shfl_xor(s, 2, 64);
    sq += __shfl_xor(sq, 1, 64); sq += __shfl_xor(sq, 2, 64);
    float mu  = s * (1.f / 128.f);
    float var = sq * (1.f / 128.f) - mu * mu;
    float rs  = rsqrtf(fmaxf(var, 0.f) + 1e-5f);

    if (grow < M) {
        const short8* g8 = reinterpret_cast<const short8*>(&g[p * 32]);
        const short8* b8 = reinterpret_cast<const short8*>(&beta[p * 32]);
        float o[32];
#pragma unroll
        for (int q = 0; q < 4; ++q) {
            short8 gg = g8[q], bb = b8[q];
#pragma unroll
            for (int j = 0; j < 8; ++j)
                o[q * 8 + j] = (v[q * 8 + j] - mu) * rs * bf2f((unsigned short)gg[j])
                               + bf2f((unsigned short)bb[j]);
        }
        float4v* o4 = reinterpret_cast<float4v*>(outf + (size_t)grow * 128 + p * 32);
#pragma unroll
        for (int q = 0; q < 8; ++q) {
            float4v ov = {o[q * 4], o[q * 4 + 1], o[q * 4 + 2], o[q * 4 + 3]};
            o4[q] = ov;
        }
        if (outb) {
            short8* ob8 = reinterpret_cast<short8*>(outb + (size_t)grow * 128 + p * 32);
#pragma unroll
            for (int q = 0; q < 4; ++q) {
                short8 oo;
#pragma unroll
                for (int j = 0; j < 8; ++j) oo[j] = (short)f2bf(o[q * 8 + j]);
                ob8[q] = oo;
            }
        }
    }
}

// ---------------------------------------------------------------------------
// CSR scan + scatter
// ---------------------------------------------------------------------------
__global__ __launch_bounds__(1024) void scan_kernel(
    const int* __restrict__ counts, int* __restrict__ offsets, int* __restrict__ pos, int n)
{
    __shared__ int wsum[16];
    __shared__ int carry_s;
    const int tid = threadIdx.x;
    const int wid = tid >> 6, lane = tid & 63;
    int vals[20];
#pragma unroll
    for (int cI = 0; cI < 20; ++cI) {
        int i = cI * 1024 + tid;
        vals[cI] = (i < n) ? counts[i] : 0;
    }
    if (tid == 0) carry_s = 0;
    __syncthreads();
#pragma unroll
    for (int cI = 0; cI < 20; ++cI) {
        int i = cI * 1024 + tid;
        int val = vals[cI];
        int x = val;
#pragma unroll
        for (int off = 1; off < 64; off <<= 1) {
            int t = __shfl_up(x, off, 64);
            if (lane >= off) x += t;
        }
        if (lane == 63) wsum[wid] = x;
        __syncthreads();
        if (wid == 0 && lane < 16) {
            int s = wsum[lane];
#pragma unroll
            for (int off = 1; off < 16; off <<= 1) {
                int t = __shfl_up(s, off, 64);
                if (lane >= off) s += t;
            }
            wsum[lane] = s;
        }
        __syncthreads();
        int prefix = (wid > 0 ? wsum[wid - 1] : 0) + carry_s;
        int ex = prefix + x - val;
        if (i < n) { offsets[i] = ex; pos[i] = ex; }
        __syncthreads();
        if (tid == 0) carry_s += wsum[15];
        __syncthreads();
    }
    if (tid == 0) offsets[n] = carry_s;
}

__global__ void scatter_kernel(const int* __restrict__ src, const int* __restrict__ dst,
                               int* __restrict__ pos, int* __restrict__ sorted_src, int E)
{
    int e = blockIdx.x * 256 + threadIdx.x;
    if (e < E) {
        int d = dst[e];
        if (d >= 0 && d < NN) {
            int p = atomicAdd(&pos[d], 1);
            if (p >= 0 && p < E) sorted_src[p] = src[e];
        }
    }
}

// ---------------------------------------------------------------------------
// All-heads graph attention, 4-deep double-buffered prefetch (8 loads/wave in
// flight). Wave per node; q [N,512]; kv [N,1024] (k|v contiguous per node).
// head = lane>>4, sub = lane&15; plain exp; head-mean via xor 16/32.
// ---------------------------------------------------------------------------
__global__ __launch_bounds__(256) void agg_kernel(
    const unsigned short* __restrict__ q, const unsigned short* __restrict__ kv,
    const int* __restrict__ offsets, const int* __restrict__ srcs,
    float* __restrict__ aggb)
{
    const int node = blockIdx.x * 4 + (threadIdx.x >> 6);
    if (node >= NN) return;
    const int lane = threadIdx.x & 63;
    const short8* q8  = reinterpret_cast<const short8*>(q);
    const short8* kv8 = reinterpret_cast<const short8*>(kv);
    const int fidx = (lane >> 4) * 16 + (lane & 15);

    short8 qv = q8[(size_t)node * 64 + fidx];
    float qf[8];
#pragma unroll
    for (int i = 0; i < 8; ++i) qf[i] = bf2f((unsigned short)qv[i]) * INV_SQRT_HC;

    int beg = offsets[node], end = offsets[node + 1];
    if (beg < 0) beg = 0;
    if (end > EE) end = EE;
    float ssum = 0.f;
    float acc[8];
#pragma unroll
    for (int i = 0; i < 8; ++i) acc[i] = 0.f;

    if (beg < end) {
        short8 kc[4], vc[4];
#pragma unroll
        for (int d = 0; d < 4; ++d) {
            int idx = beg + d; if (idx > end - 1) idx = end - 1;
            int s = srcs[idx]; if (s < 0) s = 0; if (s >= NN) s = NN - 1;
            kc[d] = kv8[(size_t)s * 128 + fidx];
            vc[d] = kv8[(size_t)s * 128 + 64 + fidx];
        }
        for (int j = beg; j < end; j += 4) {
            short8 kn[4], vn[4];
#pragma unroll
            for (int d = 0; d < 4; ++d) {          // issue next group first
                int idx = j + 4 + d; if (idx > end - 1) idx = end - 1;
                int s = srcs[idx]; if (s < 0) s = 0; if (s >= NN) s = NN - 1;
                kn[d] = kv8[(size_t)s * 128 + fidx];
                vn[d] = kv8[(size_t)s * 128 + 64 + fidx];
            }
#pragma unroll
            for (int d = 0; d < 4; ++d) {
                if (j + d < end) {                 // wave-uniform predicate
                    float dot = 0.f;
#pragma unroll
                    for (int i = 0; i < 8; ++i) dot += qf[i] * bf2f((unsigned short)kc[d][i]);
                    dot += __shfl_xor(dot, 1, 64);
                    dot += __shfl_xor(dot, 2, 64);
                    dot += __shfl_xor(dot, 4, 64);
                    dot += __shfl_xor(dot, 8, 64);
                    float pp = __expf(dot);
                    ssum += pp;
#pragma unroll
                    for (int i = 0; i < 8; ++i) acc[i] += pp * bf2f((unsigned short)vc[d][i]);
                }
            }
#pragma unroll
            for (int d = 0; d < 4; ++d) { kc[d] = kn[d]; vc[d] = vn[d]; }
        }
    }

    float inv = (ssum > 0.f) ? 1.f / ssum : 0.f;
#pragma unroll
    for (int i = 0; i < 8; ++i) acc[i] *= inv;
#pragma unroll
    for (int i = 0; i < 8; ++i) {
        acc[i] += __shfl_xor(acc[i], 16, 64);
        acc[i] += __shfl_xor(acc[i], 32, 64);
        acc[i] *= 0.25f;
    }
    if (lane < 16) {
        float4v* o = reinterpret_cast<float4v*>(aggb + (size_t)node * 128 + lane * 8);
        o[0] = (float4v){acc[0], acc[1], acc[2], acc[3]};
        o[1] = (float4v){acc[4], acc[5], acc[6], acc[7]};
    }
}

// ---------------------------------------------------------------------------
extern "C" void kernel_launch(void* const* d_in, const int* in_sizes, int n_in,
                              void* d_out, int out_size, void* d_ws, size_t ws_size,
                              hipStream_t stream)
{
    const int* edge_index = (const int*)d_in[28];
    const int* e_src = edge_index;
    const int* e_dst = edge_index + EE;

    if (n_in < 29 || in_sizes[0] != NN * DD || in_sizes[28] != 2 * EE || out_size != NN * DD)
        return;

    const size_t SZ_OFF  = (size_t)(NN + 16) * 4;
    const size_t SZ_CNT  = (size_t)NN * 4;
    const size_t SZ_SS   = (size_t)EE * 4;
    const size_t SZ_SM   = (size_t)NN * DD * 2;     //  5.12 MB
    const size_t SZ_F32  = (size_t)NN * DD * 4;     // 10.24 MB
    const size_t SZ_Q    = (size_t)NN * 512 * 2;    // 20.48 MB
    const size_t SZ_KV   = (size_t)NN * 1024 * 2;   // 40.96 MB
    const size_t SZ_HB   = (size_t)NN * GHC * 2;    // 20.48 MB
    const size_t WC_ELE  = 347136;
    const size_t SZ_WC   = WC_ELE * 2;
    const size_t SZ_WCB  = 16384 * 2 + 256;
    const size_t REQUIRED = SZ_OFF + 2 * SZ_CNT + SZ_SS + 2 * SZ_SM + SZ_WC + SZ_WCB
                          + SZ_Q + SZ_KV + 3 * SZ_F32 + SZ_SM + SZ_HB;

    if (ws_size < REQUIRED) return;

    char* w = (char*)d_ws;
    int* offsets = (int*)w;        w += SZ_OFF;
    int* counts  = (int*)w;        w += SZ_CNT;
    int* pos     = (int*)w;        w += SZ_CNT;
    int* sorted_src = (int*)w;     w += SZ_SS;
    unsigned short* xc   = (unsigned short*)w; w += SZ_SM;
    unsigned short* tec  = (unsigned short*)w; w += SZ_SM;
    unsigned short* wc   = (unsigned short*)w; w += SZ_WC;
    unsigned short* wcomb = (unsigned short*)w; w += 16384 * 2;
    unsigned short* bcomb = (unsigned short*)w; w += 256;
    unsigned short* qb   = (unsigned short*)w; w += SZ_Q;
    unsigned short* kvb  = (unsigned short*)w; w += SZ_KV;
    float*          aggb = (float*)w;          w += SZ_F32;
    float*          x1f  = (float*)w;          w += SZ_F32;
    float*          x2f  = (float*)w;          w += SZ_F32;
    unsigned short* x2b  = (unsigned short*)w; w += SZ_SM;
    unsigned short* hbuf = (unsigned short*)w; w += SZ_HB;

    unsigned short* cw = wc;
    unsigned short* qkv_w = cw; cw += 3 * 65536;
    unsigned short* qkv_b = cw; cw += 3 * 512;
    unsigned short* gs_w  = cw; cw += 16384;  unsigned short* gs_b  = cw; cw += 128;
    unsigned short* ffn_w1 = cw; cw += 65536; unsigned short* ffn_b1 = cw; cw += 512;
    unsigned short* ffn_w2 = cw; cw += 65536; unsigned short* ffn_b2 = cw; cw += 128;
    unsigned short* ln1_g = cw; cw += 128;    unsigned short* ln1_b = cw; cw += 128;
    unsigned short* ln2_g = cw; cw += 128;    unsigned short* ln2_b = cw; cw += 128;
    unsigned short* ln3_g = cw; cw += 128;    unsigned short* ln3_b = cw; cw += 128;

    const int EB = (EE + 255) / 256;
    const dim3 blk(256);
    const int MB = (NN + 63) / 64;            // 313

    WPack pack;
    const int live_idx[18] = {2,4,6, 3,5,7, 8,9, 18,19, 20,21, 22,23,24,25,26,27};
    for (int i = 0; i < 18; ++i) pack.in[i] = d_in[live_idx[i]];

    hipMemsetAsync(counts, 0, SZ_CNT, stream);
    prep_kernel<<<1664 + EB, blk, 0, stream>>>((const float*)d_in[0], (const float*)d_in[1],
                                               xc, pack, wc,
                                               (const float*)d_in[14], (const float*)d_in[15],
                                               (const float*)d_in[16], (const float*)d_in[17],
                                               wcomb, bcomb, e_dst, counts);

    scan_kernel<<<1, 1024, 0, stream>>>(counts, offsets, pos, NN);
    scatter_kernel<<<EB, blk, 0, stream>>>(e_src, e_dst, pos, sorted_src, EE);

    // TransformerConv: QKV (q->qb, k|v->kvb contiguous), agg, fused skip+LN1
    gemm3_kernel<<<dim3(MB, 12), blk, 0, stream>>>(xc, qkv_w, qkv_b, qb, kvb,
                                                   NN, 512, 1024, 512, 0);
    agg_kernel<<<(NN + 3) / 4, blk, 0, stream>>>(qb, kvb, offsets, sorted_src, aggb);
    // x1f = LN1(x_f32 + skip(xc) + agg)   [residual read in fp32 from d_in[0]]
    gemm_ln2_kernel<<<MB, blk, 0, stream>>>(xc, gs_w, gs_b, (const float*)d_in[0], aggb,
                                            ln1_g, ln1_b, x1f, nullptr, NN, DD);
    // x2 = LN2(x1f + TE@(WoWv)^T + bcomb)  -> fp32 x2f + bf16 x2b
    gemm_ln2_kernel<<<MB, blk, 0, stream>>>(tec, wcomb, bcomb, x1f, nullptr,
                                            ln2_g, ln2_b, x2f, x2b, NN, DD);
    // FFN
    gemm3_kernel<<<dim3(MB, 4), blk, 0, stream>>>(x2b, ffn_w1, ffn_b1, hbuf, nullptr,
                                                  NN, 512, 512, 99999, 1);
    gemm_ln2_kernel<<<MB, blk, 0, stream>>>(hbuf, ffn_w2, ffn_b2, x2f, nullptr,
                                            ln3_g, ln3_b, (float*)d_out, nullptr, NN, GHC);
}

// Round 13
// 313.963 us; speedup vs baseline: 1.0059x; 1.0059x over previous
//
#include <hip/hip_runtime.h>

// GraphTransformerLayer — MI355X
// r6=574 r7=418 r8=401 r9=384 r10=350 r11=308 r12=316(regress) us.
// r12 lesson: 4-deep prefetch cost VGPR 28->52, occ 57->32% -> regression.
// r13: agg = 2 waves/node (stride-2 edges, LDS combine) + cheap 1-deep
// prefetch; MLP from occupancy, not registers. fp32 residual chain kept.
#define NN 20000
#define EE 160000
#define DD 128
#define GHC 512
#define INV_SQRT_HC 0.08838834764831845f  // 1/sqrt(128)

typedef __attribute__((ext_vector_type(8))) short short8;
typedef __attribute__((ext_vector_type(4))) short short4v;
typedef __attribute__((ext_vector_type(4))) float float4v;
typedef __attribute__((ext_vector_type(4))) unsigned uint4v;

__device__ inline float bf2f(unsigned short u) {
    union { unsigned u; float f; } x; x.u = ((unsigned)u) << 16; return x.f;
}
__device__ inline unsigned short f2bf(float f) {
    union { float f; unsigned u; } x; x.f = f;
    unsigned u = x.u;
    unsigned r = (u + 0x7fffu + ((u >> 16) & 1u)) >> 16;
    return (unsigned short)r;
}

// ---------------------------------------------------------------------------
// prep: [0,1024) convert x+te -> bf16 | [1024,1600) weight pack |
//       [1600,1664) wcomb | [1664,+EB) dst histogram.  One dispatch.
// ---------------------------------------------------------------------------
struct WPack { const void* in[18]; };
__device__ __constant__ const int WSZ[18] = {
    65536, 65536, 65536, 512, 512, 512,
    16384, 128, 65536, 512, 65536, 128,
    128, 128, 128, 128, 128, 128 };

__global__ void prep_kernel(const float* __restrict__ x, const float* __restrict__ te,
                            unsigned short* __restrict__ xcout, WPack p,
                            unsigned short* __restrict__ wcout,
                            const float* __restrict__ wv, const float* __restrict__ bv,
                            const float* __restrict__ wo, const float* __restrict__ bo,
                            unsigned short* __restrict__ wcomb,
                            unsigned short* __restrict__ bcomb,
                            const int* __restrict__ e_dst, int* __restrict__ counts)
{
    const int b = blockIdx.x;
    const int tid = threadIdx.x;
    if (b < 1024) {
        const long n4half = (long)NN * DD / 4;
        short4v* out4 = reinterpret_cast<short4v*>(xcout);
        long i = (long)b * 256 + tid;
        const long stride = 1024L * 256;
        const long tot = 2 * n4half;
        for (; i < tot; i += stride) {
            const float4v* src = (i < n4half)
                ? reinterpret_cast<const float4v*>(x)
                : reinterpret_cast<const float4v*>(te) - n4half;
            float4v v = src[i];
            short4v o;
            o[0] = (short)f2bf(v[0]); o[1] = (short)f2bf(v[1]);
            o[2] = (short)f2bf(v[2]); o[3] = (short)f2bf(v[3]);
            out4[i] = o;
        }
    } else if (b < 1600) {
        const int seg = (b - 1024) >> 5;
        const int rep = (b - 1024) & 31;
        int off = 0;
#pragma unroll
        for (int s = 0; s < 18; ++s) if (s < seg) off += WSZ[s];
        const int n = WSZ[seg];
        const float* q = (const float*)p.in[seg];
        for (int i = rep * 256 + tid; i < n; i += 32 * 256)
            wcout[off + i] = f2bf(q[i]);
    } else if (b < 1664) {
        int e = (b - 1600) * 256 + tid;   // 16384 total
        int i = e >> 7, kk = e & 127;
        float s = 0.f;
        for (int j = 0; j < 128; ++j)
            s += wo[i * 128 + j] * wv[j * 128 + kk];
        wcomb[e] = f2bf(s);
        if (b == 1600 && tid < 128) {
            float t = 0.f;
            for (int j = 0; j < 128; ++j) t += wo[tid * 128 + j] * bv[j];
            bcomb[tid] = f2bf(t + bo[tid]);
        }
    } else {
        int e = (b - 1664) * 256 + tid;
        if (e < EE) {
            int d = e_dst[e];
            if (d >= 0 && d < NN) atomicAdd(&counts[d], 1);
        }
    }
}

// ---------------------------------------------------------------------------
// GEMM v3 (K=128, 128 cols/block): W slice (32KB) staged in LDS frag-major.
// Output remap: cols >= split go to out2 (stride Nout2) — splits q / kv.
// ---------------------------------------------------------------------------
__global__ __launch_bounds__(256) void gemm3_kernel(
    const unsigned short* __restrict__ A, const unsigned short* __restrict__ W,
    const unsigned short* __restrict__ bias, unsigned short* __restrict__ out,
    unsigned short* __restrict__ out2, int M, int Nout, int Nout2, int split,
    int relu)
{
    __shared__ short8 wslab[2048];                                     // 32 KB
    __shared__ __attribute__((aligned(16))) unsigned stile[4][16][36]; // 9 KB
    const int tid  = threadIdx.x;
    const int lane = tid & 63;
    const int wid  = tid >> 6;
    const int quad = lane >> 4;
    const int l15  = lane & 15;
    const int rowbase  = blockIdx.x * 64 + wid * 16;
    const int colbase0 = blockIdx.y * 128;

    unsigned short* ob; int nout, cb0;
    if (colbase0 < split) { ob = out;  nout = Nout;  cb0 = colbase0; }
    else                  { ob = out2; nout = Nout2; cb0 = colbase0 - split; }

    const short8* A8 = reinterpret_cast<const short8*>(A);
    const short8* W8 = reinterpret_cast<const short8*>(W);

#pragma unroll
    for (int rep = 0; rep < 8; ++rep) {
        int f   = rep * 256 + tid;            // 0..2047
        int fl  = f & 63;
        int fi  = (f >> 6) & 3;
        int ft  = (f >> 8) & 3;
        int ftt = f >> 10;
        int wrow = colbase0 + ftt * 64 + 16 * ft + (fl & 15);
        wslab[f] = W8[(size_t)wrow * 16 + fi * 4 + (fl >> 4)];
    }

    int arow = rowbase + l15;
    if (arow >= M) arow = M - 1;
    short8 a4[4];
#pragma unroll
    for (int i = 0; i < 4; ++i) a4[i] = A8[(size_t)arow * 16 + i * 4 + quad];

    __syncthreads();

#pragma unroll
    for (int tt = 0; tt < 2; ++tt) {
        const int colbase = colbase0 + tt * 64;
        float4v acc[4];
#pragma unroll
        for (int t = 0; t < 4; ++t) acc[t] = (float4v){0.f, 0.f, 0.f, 0.f};

#pragma unroll
        for (int i = 0; i < 4; ++i) {
#pragma unroll
            for (int t = 0; t < 4; ++t) {
                short8 b = wslab[((tt * 4 + t) * 4 + i) * 64 + lane];
                acc[t] = __builtin_amdgcn_mfma_f32_16x16x32_bf16(a4[i], b, acc[t], 0, 0, 0);
            }
        }

#pragma unroll
        for (int t = 0; t < 4; ++t) {
            float bv = bf2f(bias[colbase + 16 * t + l15]);
#pragma unroll
            for (int r = 0; r < 4; ++r) {
                float vv = acc[t][r] + bv;
                if (relu) vv = fmaxf(vv, 0.f);
                float ov = __shfl_xor(vv, 1, 64);
                if ((l15 & 1) == 0)
                    stile[wid][quad * 4 + r][8 * t + (l15 >> 1)] =
                        (unsigned)f2bf(vv) | ((unsigned)f2bf(ov) << 16);
            }
        }
        const int rr0 = lane >> 3;
        const int cd  = (lane & 7) * 4;
#pragma unroll
        for (int it = 0; it < 2; ++it) {
            int rr = rr0 + it * 8;
            int grow = rowbase + rr;
            if (grow < M) {
                uint4v v = *reinterpret_cast<const uint4v*>(&stile[wid][rr][cd]);
                *reinterpret_cast<uint4v*>(&ob[(size_t)grow * nout + cb0 + tt * 64 + cd * 2]) = v;
            }
        }
    }
}

// ---------------------------------------------------------------------------
// GEMM + residual + LN fused, W-in-LDS chunked (Nout=128; K multiple of 128).
// outf(f32) = LN(residf_f32 + (A@W^T + bias) [+ c_f32]) * g + beta;
// optional outb = bf16 copy (feeds next MFMA stage).
// ---------------------------------------------------------------------------
__global__ __launch_bounds__(256) void gemm_ln2_kernel(
    const unsigned short* __restrict__ A, const unsigned short* __restrict__ W,
    const unsigned short* __restrict__ bias,
    const float* __restrict__ residf, const float* __restrict__ c,
    const unsigned short* __restrict__ g, const unsigned short* __restrict__ beta,
    float* __restrict__ outf, unsigned short* __restrict__ outb, int M, int K)
{
    __shared__ short8 wslab[2048];                // 32 KB
    __shared__ unsigned short stile[4][16][136];
    const int tid  = threadIdx.x;
    const int lane = tid & 63;
    const int wid  = tid >> 6;
    const int quad = lane >> 4;
    const int l15  = lane & 15;
    const int rowbase = blockIdx.x * 64 + wid * 16;

    int arow = rowbase + l15;
    if (arow >= M) arow = M - 1;

    const short8* A8 = reinterpret_cast<const short8*>(A);
    const short8* W8 = reinterpret_cast<const short8*>(W);
    const int k8 = K >> 3;
    const int kchunks = K >> 7;

    float4v acc[2][4];
#pragma unroll
    for (int tt = 0; tt < 2; ++tt)
#pragma unroll
        for (int t = 0; t < 4; ++t) acc[tt][t] = (float4v){0.f, 0.f, 0.f, 0.f};

    for (int cc = 0; cc < kchunks; ++cc) {
        if (cc > 0) __syncthreads();
#pragma unroll
        for (int rep = 0; rep < 8; ++rep) {
            int f   = rep * 256 + tid;
            int fl  = f & 63;
            int fi  = (f >> 6) & 3;
            int ft  = (f >> 8) & 3;
            int ftt = f >> 10;
            int wrow = ftt * 64 + 16 * ft + (fl & 15);
            wslab[f] = W8[(size_t)wrow * k8 + cc * 16 + fi * 4 + (fl >> 4)];
        }
        short8 a4[4];
#pragma unroll
        for (int i = 0; i < 4; ++i) a4[i] = A8[(size_t)arow * k8 + cc * 16 + i * 4 + quad];
        __syncthreads();
#pragma unroll
        for (int tt = 0; tt < 2; ++tt)
#pragma unroll
            for (int i = 0; i < 4; ++i)
#pragma unroll
                for (int t = 0; t < 4; ++t) {
                    short8 b = wslab[((tt * 4 + t) * 4 + i) * 64 + lane];
                    acc[tt][t] = __builtin_amdgcn_mfma_f32_16x16x32_bf16(a4[i], b, acc[tt][t], 0, 0, 0);
                }
    }

#pragma unroll
    for (int tt = 0; tt < 2; ++tt)
#pragma unroll
        for (int t = 0; t < 4; ++t) {
            float bv = bf2f(bias[tt * 64 + 16 * t + l15]);
#pragma unroll
            for (int r = 0; r < 4; ++r)
                stile[wid][quad * 4 + r][tt * 64 + 16 * t + l15] = f2bf(acc[tt][t][r] + bv);
        }

    // LN epilogue: 4 lanes/row, 32 ch/lane (wave-private; lgkmcnt orders)
    const int r  = lane >> 2;
    const int p  = lane & 3;
    const int grow = rowbase + r;
    const int gr = (grow < M) ? grow : M - 1;

    float v[32];
    const short8* st8 = reinterpret_cast<const short8*>(&stile[wid][r][p * 32]);
#pragma unroll
    for (int q = 0; q < 4; ++q) {
        short8 sb = st8[q];
#pragma unroll
        for (int j = 0; j < 8; ++j) v[q * 8 + j] = bf2f((unsigned short)sb[j]);
    }
    const float4v* r4 = reinterpret_cast<const float4v*>(&residf[(size_t)gr * 128 + p * 32]);
#pragma unroll
    for (int q = 0; q < 8; ++q) {
        float4v rv = r4[q];
#pragma unroll
        for (int j = 0; j < 4; ++j) v[q * 4 + j] += rv[j];
    }
    if (c) {
        const float4v* c4 = reinterpret_cast<const float4v*>(&c[(size_t)gr * 128 + p * 32]);
#pragma unroll
        for (int q = 0; q < 8; ++q) {
            float4v cv = c4[q];
#pragma unroll
            for (int j = 0; j < 4; ++j) v[q * 4 + j] += cv[j];
        }
    }
    float s = 0.f, sq = 0.f;
#pragma unroll
    for (int i = 0; i < 32; ++i) { s += v[i]; sq += v[i] * v[i]; }
    s  += __shfl_xor(s, 1, 64);  s  += __shfl_xor(s, 2, 64);
    sq += __shfl_xor(sq, 1, 64); sq += __shfl_xor(sq, 2, 64);
    float mu  = s * (1.f / 128.f);
    float var = sq * (1.f / 128.f) - mu * mu;
    float rs  = rsqrtf(fmaxf(var, 0.f) + 1e-5f);

    if (grow < M) {
        const short8* g8 = reinterpret_cast<const short8*>(&g[p * 32]);
        const short8* b8 = reinterpret_cast<const short8*>(&beta[p * 32]);
        float o[32];
#pragma unroll
        for (int q = 0; q < 4; ++q) {
            short8 gg = g8[q], bb = b8[q];
#pragma unroll
            for (int j = 0; j < 8; ++j)
                o[q * 8 + j] = (v[q * 8 + j] - mu) * rs * bf2f((unsigned short)gg[j])
                               + bf2f((unsigned short)bb[j]);
        }
        float4v* o4 = reinterpret_cast<float4v*>(outf + (size_t)grow * 128 + p * 32);
#pragma unroll
        for (int q = 0; q < 8; ++q) {
            float4v ov = {o[q * 4], o[q * 4 + 1], o[q * 4 + 2], o[q * 4 + 3]};
            o4[q] = ov;
        }
        if (outb) {
            short8* ob8 = reinterpret_cast<short8*>(outb + (size_t)grow * 128 + p * 32);
#pragma unroll
            for (int q = 0; q < 4; ++q) {
                short8 oo;
#pragma unroll
                for (int j = 0; j < 8; ++j) oo[j] = (short)f2bf(o[q * 8 + j]);
                ob8[q] = oo;
            }
        }
    }
}

// ---------------------------------------------------------------------------
// CSR scan + scatter
// ---------------------------------------------------------------------------
__global__ __launch_bounds__(1024) void scan_kernel(
    const int* __restrict__ counts, int* __restrict__ offsets, int* __restrict__ pos, int n)
{
    __shared__ int wsum[16];
    __shared__ int carry_s;
    const int tid = threadIdx.x;
    const int wid = tid >> 6, lane = tid & 63;
    int vals[20];
#pragma unroll
    for (int cI = 0; cI < 20; ++cI) {
        int i = cI * 1024 + tid;
        vals[cI] = (i < n) ? counts[i] : 0;
    }
    if (tid == 0) carry_s = 0;
    __syncthreads();
#pragma unroll
    for (int cI = 0; cI < 20; ++cI) {
        int i = cI * 1024 + tid;
        int val = vals[cI];
        int x = val;
#pragma unroll
        for (int off = 1; off < 64; off <<= 1) {
            int t = __shfl_up(x, off, 64);
            if (lane >= off) x += t;
        }
        if (lane == 63) wsum[wid] = x;
        __syncthreads();
        if (wid == 0 && lane < 16) {
            int s = wsum[lane];
#pragma unroll
            for (int off = 1; off < 16; off <<= 1) {
                int t = __shfl_up(s, off, 64);
                if (lane >= off) s += t;
            }
            wsum[lane] = s;
        }
        __syncthreads();
        int prefix = (wid > 0 ? wsum[wid - 1] : 0) + carry_s;
        int ex = prefix + x - val;
        if (i < n) { offsets[i] = ex; pos[i] = ex; }
        __syncthreads();
        if (tid == 0) carry_s += wsum[15];
        __syncthreads();
    }
    if (tid == 0) offsets[n] = carry_s;
}

__global__ void scatter_kernel(const int* __restrict__ src, const int* __restrict__ dst,
                               int* __restrict__ pos, int* __restrict__ sorted_src, int E)
{
    int e = blockIdx.x * 256 + threadIdx.x;
    if (e < E) {
        int d = dst[e];
        if (d >= 0 && d < NN) {
            int p = atomicAdd(&pos[d], 1);
            if (p >= 0 && p < E) sorted_src[p] = src[e];
        }
    }
}

// ---------------------------------------------------------------------------
// All-heads graph attention: 2 WAVES PER NODE (stride-2 edge split, LDS
// combine) + 1-deep prefetch. Block = 4 waves = 2 nodes. Wave VGPR stays low
// (r12 lesson: register-funded prefetch halves occupancy).
// q [N,512]; kv [N,1024] (k|v contiguous). head = lane>>4, sub = lane&15.
// ---------------------------------------------------------------------------
__global__ __launch_bounds__(256) void agg_kernel(
    const unsigned short* __restrict__ q, const unsigned short* __restrict__ kv,
    const int* __restrict__ offsets, const int* __restrict__ srcs,
    float* __restrict__ aggb)
{
    __shared__ float sacc[4][64][8];   // per-wave partial acc   (8 KB)
    __shared__ float sssum[4][64];     // per-wave partial ssum  (1 KB)
    const int tid  = threadIdx.x;
    const int wid  = tid >> 6;
    const int lane = tid & 63;
    const int node = blockIdx.x * 2 + (wid >> 1);   // NN even -> always < NN
    const int half = wid & 1;

    const short8* q8  = reinterpret_cast<const short8*>(q);
    const short8* kv8 = reinterpret_cast<const short8*>(kv);
    const int fidx = (lane >> 4) * 16 + (lane & 15);

    short8 qv = q8[(size_t)node * 64 + fidx];
    float qf[8];
#pragma unroll
    for (int i = 0; i < 8; ++i) qf[i] = bf2f((unsigned short)qv[i]) * INV_SQRT_HC;

    int beg = offsets[node], end = offsets[node + 1];
    if (beg < 0) beg = 0;
    if (end > EE) end = EE;
    float ssum = 0.f;
    float acc[8];
#pragma unroll
    for (int i = 0; i < 8; ++i) acc[i] = 0.f;

    const int start = beg + half;     // this wave's edges: start, start+2, ...
    if (start < end) {
        int s0 = srcs[start];
        if (s0 < 0) s0 = 0;
        if (s0 >= NN) s0 = NN - 1;
        short8 kc = kv8[(size_t)s0 * 128 + fidx];
        short8 vc = kv8[(size_t)s0 * 128 + 64 + fidx];
        for (int j = start; j < end; j += 2) {
            short8 kn, vn;
            if (j + 2 < end) {        // prefetch next stride-2 edge
                int sn = srcs[j + 2];
                if (sn < 0) sn = 0;
                if (sn >= NN) sn = NN - 1;
                kn = kv8[(size_t)sn * 128 + fidx];
                vn = kv8[(size_t)sn * 128 + 64 + fidx];
            }
            float dot = 0.f;
#pragma unroll
            for (int i = 0; i < 8; ++i) dot += qf[i] * bf2f((unsigned short)kc[i]);
            dot += __shfl_xor(dot, 1, 64);
            dot += __shfl_xor(dot, 2, 64);
            dot += __shfl_xor(dot, 4, 64);
            dot += __shfl_xor(dot, 8, 64);
            float pp = __expf(dot);
            ssum += pp;
#pragma unroll
            for (int i = 0; i < 8; ++i) acc[i] += pp * bf2f((unsigned short)vc[i]);
            kc = kn; vc = vn;
        }
    }

    // publish partials; even wave combines
#pragma unroll
    for (int i = 0; i < 8; ++i) sacc[wid][lane][i] = acc[i];
    sssum[wid][lane] = ssum;
    __syncthreads();
    if (half == 0) {
#pragma unroll
        for (int i = 0; i < 8; ++i) acc[i] += sacc[wid ^ 1][lane][i];
        ssum += sssum[wid ^ 1][lane];

        float inv = (ssum > 0.f) ? 1.f / ssum : 0.f;
#pragma unroll
        for (int i = 0; i < 8; ++i) acc[i] *= inv;
#pragma unroll
        for (int i = 0; i < 8; ++i) {
            acc[i] += __shfl_xor(acc[i], 16, 64);
            acc[i] += __shfl_xor(acc[i], 32, 64);
            acc[i] *= 0.25f;
        }
        if (lane < 16) {
            float4v* o = reinterpret_cast<float4v*>(aggb + (size_t)node * 128 + lane * 8);
            o[0] = (float4v){acc[0], acc[1], acc[2], acc[3]};
            o[1] = (float4v){acc[4], acc[5], acc[6], acc[7]};
        }
    }
}

// ---------------------------------------------------------------------------
extern "C" void kernel_launch(void* const* d_in, const int* in_sizes, int n_in,
                              void* d_out, int out_size, void* d_ws, size_t ws_size,
                              hipStream_t stream)
{
    const int* edge_index = (const int*)d_in[28];
    const int* e_src = edge_index;
    const int* e_dst = edge_index + EE;

    if (n_in < 29 || in_sizes[0] != NN * DD || in_sizes[28] != 2 * EE || out_size != NN * DD)
        return;

    const size_t SZ_OFF  = (size_t)(NN + 16) * 4;
    const size_t SZ_CNT  = (size_t)NN * 4;
    const size_t SZ_SS   = (size_t)EE * 4;
    const size_t SZ_SM   = (size_t)NN * DD * 2;     //  5.12 MB
    const size_t SZ_F32  = (size_t)NN * DD * 4;     // 10.24 MB
    const size_t SZ_Q    = (size_t)NN * 512 * 2;    // 20.48 MB
    const size_t SZ_KV   = (size_t)NN * 1024 * 2;   // 40.96 MB
    const size_t SZ_HB   = (size_t)NN * GHC * 2;    // 20.48 MB
    const size_t WC_ELE  = 347136;
    const size_t SZ_WC   = WC_ELE * 2;
    const size_t SZ_WCB  = 16384 * 2 + 256;
    const size_t REQUIRED = SZ_OFF + 2 * SZ_CNT + SZ_SS + 2 * SZ_SM + SZ_WC + SZ_WCB
                          + SZ_Q + SZ_KV + 3 * SZ_F32 + SZ_SM + SZ_HB;

    if (ws_size < REQUIRED) return;

    char* w = (char*)d_ws;
    int* offsets = (int*)w;        w += SZ_OFF;
    int* counts  = (int*)w;        w += SZ_CNT;
    int* pos     = (int*)w;        w += SZ_CNT;
    int* sorted_src = (int*)w;     w += SZ_SS;
    unsigned short* xc   = (unsigned short*)w; w += SZ_SM;
    unsigned short* tec  = (unsigned short*)w; w += SZ_SM;
    unsigned short* wc   = (unsigned short*)w; w += SZ_WC;
    unsigned short* wcomb = (unsigned short*)w; w += 16384 * 2;
    unsigned short* bcomb = (unsigned short*)w; w += 256;
    unsigned short* qb   = (unsigned short*)w; w += SZ_Q;
    unsigned short* kvb  = (unsigned short*)w; w += SZ_KV;
    float*          aggb = (float*)w;          w += SZ_F32;
    float*          x1f  = (float*)w;          w += SZ_F32;
    float*          x2f  = (float*)w;          w += SZ_F32;
    unsigned short* x2b  = (unsigned short*)w; w += SZ_SM;
    unsigned short* hbuf = (unsigned short*)w; w += SZ_HB;

    unsigned short* cw = wc;
    unsigned short* qkv_w = cw; cw += 3 * 65536;
    unsigned short* qkv_b = cw; cw += 3 * 512;
    unsigned short* gs_w  = cw; cw += 16384;  unsigned short* gs_b  = cw; cw += 128;
    unsigned short* ffn_w1 = cw; cw += 65536; unsigned short* ffn_b1 = cw; cw += 512;
    unsigned short* ffn_w2 = cw; cw += 65536; unsigned short* ffn_b2 = cw; cw += 128;
    unsigned short* ln1_g = cw; cw += 128;    unsigned short* ln1_b = cw; cw += 128;
    unsigned short* ln2_g = cw; cw += 128;    unsigned short* ln2_b = cw; cw += 128;
    unsigned short* ln3_g = cw; cw += 128;    unsigned short* ln3_b = cw; cw += 128;

    const int EB = (EE + 255) / 256;
    const dim3 blk(256);
    const int MB = (NN + 63) / 64;            // 313

    WPack pack;
    const int live_idx[18] = {2,4,6, 3,5,7, 8,9, 18,19, 20,21, 22,23,24,25,26,27};
    for (int i = 0; i < 18; ++i) pack.in[i] = d_in[live_idx[i]];

    hipMemsetAsync(counts, 0, SZ_CNT, stream);
    prep_kernel<<<1664 + EB, blk, 0, stream>>>((const float*)d_in[0], (const float*)d_in[1],
                                               xc, pack, wc,
                                               (const float*)d_in[14], (const float*)d_in[15],
                                               (const float*)d_in[16], (const float*)d_in[17],
                                               wcomb, bcomb, e_dst, counts);

    scan_kernel<<<1, 1024, 0, stream>>>(counts, offsets, pos, NN);
    scatter_kernel<<<EB, blk, 0, stream>>>(e_src, e_dst, pos, sorted_src, EE);

    // TransformerConv: QKV (q->qb, k|v->kvb contiguous), agg, fused skip+LN1
    gemm3_kernel<<<dim3(MB, 12), blk, 0, stream>>>(xc, qkv_w, qkv_b, qb, kvb,
                                                   NN, 512, 1024, 512, 0);
    agg_kernel<<<NN / 2, blk, 0, stream>>>(qb, kvb, offsets, sorted_src, aggb);
    // x1f = LN1(x_f32 + skip(xc) + agg)   [residual read in fp32 from d_in[0]]
    gemm_ln2_kernel<<<MB, blk, 0, stream>>>(xc, gs_w, gs_b, (const float*)d_in[0], aggb,
                                            ln1_g, ln1_b, x1f, nullptr, NN, DD);
    // x2 = LN2(x1f + TE@(WoWv)^T + bcomb)  -> fp32 x2f + bf16 x2b
    gemm_ln2_kernel<<<MB, blk, 0, stream>>>(tec, wcomb, bcomb, x1f, nullptr,
                                            ln2_g, ln2_b, x2f, x2b, NN, DD);
    // FFN
    gemm3_kernel<<<dim3(MB, 4), blk, 0, stream>>>(x2b, ffn_w1, ffn_b1, hbuf, nullptr,
                                                  NN, 512, 512, 99999, 1);
    gemm_ln2_kernel<<<MB, blk, 0, stream>>>(hbuf, ffn_w2, ffn_b2, x2f, nullptr,
                                            ln3_g, ln3_b, (float*)d_out, nullptr, NN, GHC);
}

// Round 15
// 294.753 us; speedup vs baseline: 1.0715x; 1.0652x over previous
//
#include <hip/hip_runtime.h>

// GraphTransformerLayer — MI355X
// r6=574 r7=418 r8=401 r9=384 r10=350 r11=308 r12=316 r13=314 r14=compile-err.
// agg pinned at 52us across occ 32..68% with FETCH=166MB -> random-gather
// throughput ceiling; r14/r15: kv stored fp8 e4m3 (x256) -> 1KB/edge, one
// dwordx4/lane; lane-parallel src preload. r15 fixes cvt_pk_f32_fp8 imm-arg.
#define NN 20000
#define EE 160000
#define DD 128
#define GHC 512
#define INV_SQRT_HC 0.08838834764831845f  // 1/sqrt(128)

typedef __attribute__((ext_vector_type(8))) short short8;
typedef __attribute__((ext_vector_type(4))) short short4v;
typedef __attribute__((ext_vector_type(4))) float float4v;
typedef __attribute__((ext_vector_type(2))) float float2v;
typedef __attribute__((ext_vector_type(4))) unsigned uint4v;
typedef __attribute__((ext_vector_type(2))) unsigned uint2v;

__device__ inline float bf2f(unsigned short u) {
    union { unsigned u; float f; } x; x.u = ((unsigned)u) << 16; return x.f;
}
__device__ inline unsigned short f2bf(float f) {
    union { float f; unsigned u; } x; x.f = f;
    unsigned u = x.u;
    unsigned r = (u + 0x7fffu + ((u >> 16) & 1u)) >> 16;
    return (unsigned short)r;
}

// ---------------- fp8 e4m3 pack/unpack (HW cvt on gfx950; sw fallback) -----
#if defined(__has_builtin)
#if __has_builtin(__builtin_amdgcn_cvt_pk_f32_fp8) && __has_builtin(__builtin_amdgcn_cvt_pk_fp8_f32)
#define HW_FP8 1
#endif
#endif
#ifndef HW_FP8
#define HW_FP8 0
#endif

#if !HW_FP8
__device__ inline unsigned char sw_enc_fp8(float f) {
    if (!(f == f)) return 0x7f;
    unsigned s = (f < 0.f) ? 0x80u : 0u;
    float a = fabsf(f);
    if (a >= 448.f) return (unsigned char)(s | 0x7e);
    if (a < 5.96046448e-8f) return (unsigned char)s;
    int e; frexpf(a, &e);
    int E = e - 1;
    if (E < -6) E = -6;
    float q = ldexpf(rintf(ldexpf(a, 3 - E)), E - 3);
    if (q == 0.f) return (unsigned char)s;
    union { float f; unsigned u; } x; x.f = q;
    int qe = (int)((x.u >> 23) & 0xff) - 127;
    if (qe < -6) {
        unsigned mant = (unsigned)rintf(ldexpf(q, 9));
        return (unsigned char)(s | mant);
    }
    unsigned mant = (x.u >> 20) & 7;
    int ebits = qe + 7;
    if (ebits > 15) { ebits = 15; mant = 6; }
    return (unsigned char)(s | ((unsigned)ebits << 3) | mant);
}
__device__ inline float sw_dec_fp8(unsigned char u) {
    unsigned s = u >> 7, e = (u >> 3) & 15, m = u & 7;
    float v = e ? ldexpf((float)(8 + m), (int)e - 10) : ldexpf((float)m, -9);
    return s ? -v : v;
}
#endif

__device__ inline unsigned short fp8_enc2(float a, float b) {
#if HW_FP8
    int r = __builtin_amdgcn_cvt_pk_fp8_f32(a, b, 0, false);
    return (unsigned short)(r & 0xffff);
#else
    return (unsigned short)(sw_enc_fp8(a) | ((unsigned)sw_enc_fp8(b) << 8));
#endif
}
// NOTE: the `hi` (word-sel) operand of cvt_pk_f32_fp8 must be an IMMEDIATE
// (r14 compile error) -> two variants with literal false/true.
__device__ inline float2v fp8_dec2_lo(unsigned w) {
#if HW_FP8
    return __builtin_amdgcn_cvt_pk_f32_fp8((int)w, false);
#else
    float2v r;
    r[0] = sw_dec_fp8((unsigned char)(w & 0xff));
    r[1] = sw_dec_fp8((unsigned char)((w >> 8) & 0xff));
    return r;
#endif
}
__device__ inline float2v fp8_dec2_hi(unsigned w) {
#if HW_FP8
    return __builtin_amdgcn_cvt_pk_f32_fp8((int)w, true);
#else
    float2v r;
    r[0] = sw_dec_fp8((unsigned char)((w >> 16) & 0xff));
    r[1] = sw_dec_fp8((unsigned char)(w >> 24));
    return r;
#endif
}

// ---------------------------------------------------------------------------
// prep: [0,1024) convert x+te -> bf16 | [1024,1600) weight pack |
//       [1600,1664) wcomb | [1664,+EB) dst histogram.  One dispatch.
// ---------------------------------------------------------------------------
struct WPack { const void* in[18]; };
__device__ __constant__ const int WSZ[18] = {
    65536, 65536, 65536, 512, 512, 512,
    16384, 128, 65536, 512, 65536, 128,
    128, 128, 128, 128, 128, 128 };

__global__ void prep_kernel(const float* __restrict__ x, const float* __restrict__ te,
                            unsigned short* __restrict__ xcout, WPack p,
                            unsigned short* __restrict__ wcout,
                            const float* __restrict__ wv, const float* __restrict__ bv,
                            const float* __restrict__ wo, const float* __restrict__ bo,
                            unsigned short* __restrict__ wcomb,
                            unsigned short* __restrict__ bcomb,
                            const int* __restrict__ e_dst, int* __restrict__ counts)
{
    const int b = blockIdx.x;
    const int tid = threadIdx.x;
    if (b < 1024) {
        const long n4half = (long)NN * DD / 4;
        short4v* out4 = reinterpret_cast<short4v*>(xcout);
        long i = (long)b * 256 + tid;
        const long stride = 1024L * 256;
        const long tot = 2 * n4half;
        for (; i < tot; i += stride) {
            const float4v* src = (i < n4half)
                ? reinterpret_cast<const float4v*>(x)
                : reinterpret_cast<const float4v*>(te) - n4half;
            float4v v = src[i];
            short4v o;
            o[0] = (short)f2bf(v[0]); o[1] = (short)f2bf(v[1]);
            o[2] = (short)f2bf(v[2]); o[3] = (short)f2bf(v[3]);
            out4[i] = o;
        }
    } else if (b < 1600) {
        const int seg = (b - 1024) >> 5;
        const int rep = (b - 1024) & 31;
        int off = 0;
#pragma unroll
        for (int s = 0; s < 18; ++s) if (s < seg) off += WSZ[s];
        const int n = WSZ[seg];
        const float* q = (const float*)p.in[seg];
        for (int i = rep * 256 + tid; i < n; i += 32 * 256)
            wcout[off + i] = f2bf(q[i]);
    } else if (b < 1664) {
        int e = (b - 1600) * 256 + tid;   // 16384 total
        int i = e >> 7, kk = e & 127;
        float s = 0.f;
        for (int j = 0; j < 128; ++j)
            s += wo[i * 128 + j] * wv[j * 128 + kk];
        wcomb[e] = f2bf(s);
        if (b == 1600 && tid < 128) {
            float t = 0.f;
            for (int j = 0; j < 128; ++j) t += wo[tid * 128 + j] * bv[j];
            bcomb[tid] = f2bf(t + bo[tid]);
        }
    } else {
        int e = (b - 1664) * 256 + tid;
        if (e < EE) {
            int d = e_dst[e];
            if (d >= 0 && d < NN) atomicAdd(&counts[d], 1);
        }
    }
}

// ---------------------------------------------------------------------------
// GEMM v3 (K=128, 128 cols/block): W slice (32KB) staged in LDS frag-major.
// cols < split  -> bf16 `out` (stride Nout).
// cols >= split -> fp8 kv buffer [M][1024B]: unit (head*16+sub)*16 holds
//                  k8|v8; this tile writes 8B chunks (which=k/v) x256 scaled.
// ---------------------------------------------------------------------------
__global__ __launch_bounds__(256) void gemm3_kernel(
    const unsigned short* __restrict__ A, const unsigned short* __restrict__ W,
    const unsigned short* __restrict__ bias, unsigned short* __restrict__ out,
    unsigned char* __restrict__ kvout, int M, int Nout, int split, int relu)
{
    __shared__ short8 wslab[2048];                                     // 32 KB
    __shared__ __attribute__((aligned(16))) unsigned stile[4][16][36]; // 9 KB
    const int tid  = threadIdx.x;
    const int lane = tid & 63;
    const int wid  = tid >> 6;
    const int quad = lane >> 4;
    const int l15  = lane & 15;
    const int rowbase  = blockIdx.x * 64 + wid * 16;
    const int colbase0 = blockIdx.y * 128;
    const bool isfp8 = (colbase0 >= split);
    const int kvcol = colbase0 - split;              // 0..1023 when fp8
    const int which = isfp8 ? (kvcol >> 9) : 0;      // 0=k, 1=v
    const int head  = isfp8 ? ((kvcol & 511) >> 7) : 0;

    const short8* A8 = reinterpret_cast<const short8*>(A);
    const short8* W8 = reinterpret_cast<const short8*>(W);

#pragma unroll
    for (int rep = 0; rep < 8; ++rep) {
        int f   = rep * 256 + tid;            // 0..2047
        int fl  = f & 63;
        int fi  = (f >> 6) & 3;
        int ft  = (f >> 8) & 3;
        int ftt = f >> 10;
        int wrow = colbase0 + ftt * 64 + 16 * ft + (fl & 15);
        wslab[f] = W8[(size_t)wrow * 16 + fi * 4 + (fl >> 4)];
    }

    int arow = rowbase + l15;
    if (arow >= M) arow = M - 1;
    short8 a4[4];
#pragma unroll
    for (int i = 0; i < 4; ++i) a4[i] = A8[(size_t)arow * 16 + i * 4 + quad];

    __syncthreads();

#pragma unroll
    for (int tt = 0; tt < 2; ++tt) {
        const int colbase = colbase0 + tt * 64;
        float4v acc[4];
#pragma unroll
        for (int t = 0; t < 4; ++t) acc[t] = (float4v){0.f, 0.f, 0.f, 0.f};

#pragma unroll
        for (int i = 0; i < 4; ++i) {
#pragma unroll
            for (int t = 0; t < 4; ++t) {
                short8 b = wslab[((tt * 4 + t) * 4 + i) * 64 + lane];
                acc[t] = __builtin_amdgcn_mfma_f32_16x16x32_bf16(a4[i], b, acc[t], 0, 0, 0);
            }
        }

        if (!isfp8) {
            // bf16 epilogue: shfl-pack col pairs -> dword LDS -> b128 stores
#pragma unroll
            for (int t = 0; t < 4; ++t) {
                float bv = bf2f(bias[colbase + 16 * t + l15]);
#pragma unroll
                for (int r = 0; r < 4; ++r) {
                    float vv = acc[t][r] + bv;
                    if (relu) vv = fmaxf(vv, 0.f);
                    float ov = __shfl_xor(vv, 1, 64);
                    if ((l15 & 1) == 0)
                        stile[wid][quad * 4 + r][8 * t + (l15 >> 1)] =
                            (unsigned)f2bf(vv) | ((unsigned)f2bf(ov) << 16);
                }
            }
            const int rr0 = lane >> 3;
            const int cd  = (lane & 7) * 4;
#pragma unroll
            for (int it = 0; it < 2; ++it) {
                int rr = rr0 + it * 8;
                int grow = rowbase + rr;
                if (grow < M) {
                    uint4v v = *reinterpret_cast<const uint4v*>(&stile[wid][rr][cd]);
                    *reinterpret_cast<uint4v*>(&out[(size_t)grow * Nout + colbase0 + tt * 64 + cd * 2]) = v;
                }
            }
        } else {
            // fp8 epilogue: encode pairs (x256), stage ushorts, 8B chunk stores
            unsigned short* fp = reinterpret_cast<unsigned short*>(&stile[wid][0][0]);
#pragma unroll
            for (int t = 0; t < 4; ++t) {
                float bv = bf2f(bias[colbase + 16 * t + l15]);
#pragma unroll
                for (int r = 0; r < 4; ++r) {
                    float vv = (acc[t][r] + bv) * 256.f;
                    float ov = __shfl_xor(vv, 1, 64);
                    if ((l15 & 1) == 0)
                        fp[(quad * 4 + r) * 72 + ((16 * t + l15) >> 1)] = fp8_enc2(vv, ov);
                }
            }
#pragma unroll
            for (int it = 0; it < 2; ++it) {
                int u = lane + it * 64;          // 0..127
                int row = u >> 3;                // 0..15
                int subpart = u & 7;             // 0..7
                int grow = rowbase + row;
                if (grow < M) {
                    uint2v v = *reinterpret_cast<const uint2v*>(&fp[row * 72 + subpart * 4]);
                    size_t ro = (size_t)grow * 1024
                              + (size_t)(head * 16 + tt * 8 + subpart) * 16 + which * 8;
                    *reinterpret_cast<uint2v*>(kvout + ro) = v;
                }
            }
        }
    }
}

// ---------------------------------------------------------------------------
// GEMM + residual + LN fused, W-in-LDS chunked (Nout=128; K multiple of 128).
// ---------------------------------------------------------------------------
__global__ __launch_bounds__(256) void gemm_ln2_kernel(
    const unsigned short* __restrict__ A, const unsigned short* __restrict__ W,
    const unsigned short* __restrict__ bias,
    const float* __restrict__ residf, const float* __restrict__ c,
    const unsigned short* __restrict__ g, const unsigned short* __restrict__ beta,
    float* __restrict__ outf, unsigned short* __restrict__ outb, int M, int K)
{
    __shared__ short8 wslab[2048];                // 32 KB
    __shared__ unsigned short stile[4][16][136];
    const int tid  = threadIdx.x;
    const int lane = tid & 63;
    const int wid  = tid >> 6;
    const int quad = lane >> 4;
    const int l15  = lane & 15;
    const int rowbase = blockIdx.x * 64 + wid * 16;

    int arow = rowbase + l15;
    if (arow >= M) arow = M - 1;

    const short8* A8 = reinterpret_cast<const short8*>(A);
    const short8* W8 = reinterpret_cast<const short8*>(W);
    const int k8 = K >> 3;
    const int kchunks = K >> 7;

    float4v acc[2][4];
#pragma unroll
    for (int tt = 0; tt < 2; ++tt)
#pragma unroll
        for (int t = 0; t < 4; ++t) acc[tt][t] = (float4v){0.f, 0.f, 0.f, 0.f};

    for (int cc = 0; cc < kchunks; ++cc) {
        if (cc > 0) __syncthreads();
#pragma unroll
        for (int rep = 0; rep < 8; ++rep) {
            int f   = rep * 256 + tid;
            int fl  = f & 63;
            int fi  = (f >> 6) & 3;
            int ft  = (f >> 8) & 3;
            int ftt = f >> 10;
            int wrow = ftt * 64 + 16 * ft + (fl & 15);
            wslab[f] = W8[(size_t)wrow * k8 + cc * 16 + fi * 4 + (fl >> 4)];
        }
        short8 a4[4];
#pragma unroll
        for (int i = 0; i < 4; ++i) a4[i] = A8[(size_t)arow * k8 + cc * 16 + i * 4 + quad];
        __syncthreads();
#pragma unroll
        for (int tt = 0; tt < 2; ++tt)
#pragma unroll
            for (int i = 0; i < 4; ++i)
#pragma unroll
                for (int t = 0; t < 4; ++t) {
                    short8 b = wslab[((tt * 4 + t) * 4 + i) * 64 + lane];
                    acc[tt][t] = __builtin_amdgcn_mfma_f32_16x16x32_bf16(a4[i], b, acc[tt][t], 0, 0, 0);
                }
    }

#pragma unroll
    for (int tt = 0; tt < 2; ++tt)
#pragma unroll
        for (int t = 0; t < 4; ++t) {
            float bv = bf2f(bias[tt * 64 + 16 * t + l15]);
#pragma unroll
            for (int r = 0; r < 4; ++r)
                stile[wid][quad * 4 + r][tt * 64 + 16 * t + l15] = f2bf(acc[tt][t][r] + bv);
        }

    const int r  = lane >> 2;
    const int p  = lane & 3;
    const int grow = rowbase + r;
    const int gr = (grow < M) ? grow : M - 1;

    float v[32];
    const short8* st8 = reinterpret_cast<const short8*>(&stile[wid][r][p * 32]);
#pragma unroll
    for (int q = 0; q < 4; ++q) {
        short8 sb = st8[q];
#pragma unroll
        for (int j = 0; j < 8; ++j) v[q * 8 + j] = bf2f((unsigned short)sb[j]);
    }
    const float4v* r4 = reinterpret_cast<const float4v*>(&residf[(size_t)gr * 128 + p * 32]);
#pragma unroll
    for (int q = 0; q < 8; ++q) {
        float4v rv = r4[q];
#pragma unroll
        for (int j = 0; j < 4; ++j) v[q * 4 + j] += rv[j];
    }
    if (c) {
        const float4v* c4 = reinterpret_cast<const float4v*>(&c[(size_t)gr * 128 + p * 32]);
#pragma unroll
        for (int q = 0; q < 8; ++q) {
            float4v cv = c4[q];
#pragma unroll
            for (int j = 0; j < 4; ++j) v[q * 4 + j] += cv[j];
        }
    }
    float s = 0.f, sq = 0.f;
#pragma unroll
    for (int i = 0; i < 32; ++i) { s += v[i]; sq += v[i] * v[i]; }
    s  += __shfl_xor(s, 1, 64);  s  += __shfl_xor(s, 2, 64);
    sq += __shfl_xor(sq, 1, 64); sq += __shfl_xor(sq, 2, 64);
    float mu  = s * (1.f / 128.f);
    float var = sq * (1.f / 128.f) - mu * mu;
    float rs  = rsqrtf(fmaxf(var, 0.f) + 1e-5f);

    if (grow < M) {
        const short8* g8 = reinterpret_cast<const short8*>(&g[p * 32]);
        const short8* b8 = reinterpret_cast<const short8*>(&beta[p * 32]);
        float o[32];
#pragma unroll
        for (int q = 0; q < 4; ++q) {
            short8 gg = g8[q], bb = b8[q];
#pragma unroll
            for (int j = 0; j < 8; ++j)
                o[q * 8 + j] = (v[q * 8 + j] - mu) * rs * bf2f((unsigned short)gg[j])
                               + bf2f((unsigned short)bb[j]);
        }
        float4v* o4 = reinterpret_cast<float4v*>(outf + (size_t)grow * 128 + p * 32);
#pragma unroll
        for (int q = 0; q < 8; ++q) {
            float4v ov = {o[q * 4], o[q * 4 + 1], o[q * 4 + 2], o[q * 4 + 3]};
            o4[q] = ov;
        }
        if (outb) {
            short8* ob8 = reinterpret_cast<short8*>(outb + (size_t)grow * 128 + p * 32);
#pragma unroll
            for (int q = 0; q < 4; ++q) {
                short8 oo;
#pragma unroll
                for (int j = 0; j < 8; ++j) oo[j] = (short)f2bf(o[q * 8 + j]);
                ob8[q] = oo;
            }
        }
    }
}

// ---------------------------------------------------------------------------
// CSR scan + scatter
// ---------------------------------------------------------------------------
__global__ __launch_bounds__(1024) void scan_kernel(
    const int* __restrict__ counts, int* __restrict__ offsets, int* __restrict__ pos, int n)
{
    __shared__ int wsum[16];
    __shared__ int carry_s;
    const int tid = threadIdx.x;
    const int wid = tid >> 6, lane = tid & 63;
    int vals[20];
#pragma unroll
    for (int cI = 0; cI < 20; ++cI) {
        int i = cI * 1024 + tid;
        vals[cI] = (i < n) ? counts[i] : 0;
    }
    if (tid == 0) carry_s = 0;
    __syncthreads();
#pragma unroll
    for (int cI = 0; cI < 20; ++cI) {
        int i = cI * 1024 + tid;
        int val = vals[cI];
        int x = val;
#pragma unroll
        for (int off = 1; off < 64; off <<= 1) {
            int t = __shfl_up(x, off, 64);
            if (lane >= off) x += t;
        }
        if (lane == 63) wsum[wid] = x;
        __syncthreads();
        if (wid == 0 && lane < 16) {
            int s = wsum[lane];
#pragma unroll
            for (int off = 1; off < 16; off <<= 1) {
                int t = __shfl_up(s, off, 64);
                if (lane >= off) s += t;
            }
            wsum[lane] = s;
        }
        __syncthreads();
        int prefix = (wid > 0 ? wsum[wid - 1] : 0) + carry_s;
        int ex = prefix + x - val;
        if (i < n) { offsets[i] = ex; pos[i] = ex; }
        __syncthreads();
        if (tid == 0) carry_s += wsum[15];
        __syncthreads();
    }
    if (tid == 0) offsets[n] = carry_s;
}

__global__ void scatter_kernel(const int* __restrict__ src, const int* __restrict__ dst,
                               int* __restrict__ pos, int* __restrict__ sorted_src, int E)
{
    int e = blockIdx.x * 256 + threadIdx.x;
    if (e < E) {
        int d = dst[e];
        if (d >= 0 && d < NN) {
            int p = atomicAdd(&pos[d], 1);
            if (p >= 0 && p < E) sorted_src[p] = src[e];
        }
    }
}

// ---------------------------------------------------------------------------
// All-heads graph attention over fp8 kv: 2 waves/node (stride-2), lane-
// parallel src preload (no src->kv dependent chain), 1-deep kv prefetch.
// q bf16 [N,512]; kv fp8 [N,1024B] unit (head*16+sub)*16 = k8|v8.
// qf folds INV_SQRT_HC * 2^-8; final inv folds another 2^-8.
// ---------------------------------------------------------------------------
__device__ inline void agg_edge(const uint4v& cur, const float* qf,
                                float* acc, float& ssum)
{
    float2v k01 = fp8_dec2_lo(cur[0]);
    float2v k23 = fp8_dec2_hi(cur[0]);
    float2v k45 = fp8_dec2_lo(cur[1]);
    float2v k67 = fp8_dec2_hi(cur[1]);
    float dot = qf[0] * k01[0] + qf[1] * k01[1] + qf[2] * k23[0] + qf[3] * k23[1]
              + qf[4] * k45[0] + qf[5] * k45[1] + qf[6] * k67[0] + qf[7] * k67[1];
    dot += __shfl_xor(dot, 1, 64);
    dot += __shfl_xor(dot, 2, 64);
    dot += __shfl_xor(dot, 4, 64);
    dot += __shfl_xor(dot, 8, 64);
    float pp = __expf(dot);
    ssum += pp;
    float2v v01 = fp8_dec2_lo(cur[2]);
    float2v v23 = fp8_dec2_hi(cur[2]);
    float2v v45 = fp8_dec2_lo(cur[3]);
    float2v v67 = fp8_dec2_hi(cur[3]);
    acc[0] += pp * v01[0]; acc[1] += pp * v01[1];
    acc[2] += pp * v23[0]; acc[3] += pp * v23[1];
    acc[4] += pp * v45[0]; acc[5] += pp * v45[1];
    acc[6] += pp * v67[0]; acc[7] += pp * v67[1];
}

__global__ __launch_bounds__(256) void agg_kernel(
    const unsigned short* __restrict__ q, const unsigned char* __restrict__ kvb,
    const int* __restrict__ offsets, const int* __restrict__ srcs,
    float* __restrict__ aggb)
{
    __shared__ float sacc[4][64][8];
    __shared__ float sssum[4][64];
    const int tid  = threadIdx.x;
    const int wid  = tid >> 6;
    const int lane = tid & 63;
    const int node = blockIdx.x * 2 + (wid >> 1);
    const int half = wid & 1;

    const short8* q8  = reinterpret_cast<const short8*>(q);
    const uint4v* kv4 = reinterpret_cast<const uint4v*>(kvb);   // 64 units/row
    const int fidx = (lane >> 4) * 16 + (lane & 15);

    short8 qv = q8[(size_t)node * 64 + fidx];
    float qf[8];
#pragma unroll
    for (int i = 0; i < 8; ++i)
        qf[i] = bf2f((unsigned short)qv[i]) * (INV_SQRT_HC / 256.f);

    int beg = offsets[node], end = offsets[node + 1];
    if (beg < 0) beg = 0;
    if (end > EE) end = EE;
    float ssum = 0.f;
    float acc[8];
#pragma unroll
    for (int i = 0; i < 8; ++i) acc[i] = 0.f;

    const int start = beg + half;
    int nce = (end > start) ? ((end - start + 1) >> 1) : 0;
    int ncap = (nce > 64) ? 64 : nce;

    int sv = 0;
    if (lane < ncap) {
        int s = srcs[start + 2 * lane];
        if (s < 0) s = 0;
        if (s >= NN) s = NN - 1;
        sv = s;
    }
    if (ncap > 0) {
        int s0 = __shfl(sv, 0, 64);
        uint4v cur = kv4[(size_t)s0 * 64 + fidx];
        for (int i = 0; i < ncap; ++i) {
            uint4v nxt;
            if (i + 1 < ncap) {
                int sn = __shfl(sv, i + 1, 64);
                nxt = kv4[(size_t)sn * 64 + fidx];
            }
            agg_edge(cur, qf, acc, ssum);
            cur = nxt;
        }
    }
    for (int j = start + 128; j < end; j += 2) {   // pathological-degree tail
        int s = srcs[j];
        if (s < 0) s = 0;
        if (s >= NN) s = NN - 1;
        uint4v cur = kv4[(size_t)s * 64 + fidx];
        agg_edge(cur, qf, acc, ssum);
    }

    // publish partials; even wave combines
#pragma unroll
    for (int i = 0; i < 8; ++i) sacc[wid][lane][i] = acc[i];
    sssum[wid][lane] = ssum;
    __syncthreads();
    if (half == 0) {
#pragma unroll
        for (int i = 0; i < 8; ++i) acc[i] += sacc[wid ^ 1][lane][i];
        ssum += sssum[wid ^ 1][lane];

        float inv = (ssum > 0.f) ? 1.f / (256.f * ssum) : 0.f;   // undo x256
#pragma unroll
        for (int i = 0; i < 8; ++i) acc[i] *= inv;
#pragma unroll
        for (int i = 0; i < 8; ++i) {
            acc[i] += __shfl_xor(acc[i], 16, 64);
            acc[i] += __shfl_xor(acc[i], 32, 64);
            acc[i] *= 0.25f;
        }
        if (lane < 16) {
            float4v* o = reinterpret_cast<float4v*>(aggb + (size_t)node * 128 + lane * 8);
            o[0] = (float4v){acc[0], acc[1], acc[2], acc[3]};
            o[1] = (float4v){acc[4], acc[5], acc[6], acc[7]};
        }
    }
}

// ---------------------------------------------------------------------------
extern "C" void kernel_launch(void* const* d_in, const int* in_sizes, int n_in,
                              void* d_out, int out_size, void* d_ws, size_t ws_size,
                              hipStream_t stream)
{
    const int* edge_index = (const int*)d_in[28];
    const int* e_src = edge_index;
    const int* e_dst = edge_index + EE;

    if (n_in < 29 || in_sizes[0] != NN * DD || in_sizes[28] != 2 * EE || out_size != NN * DD)
        return;

    const size_t SZ_OFF  = (size_t)(NN + 16) * 4;
    const size_t SZ_CNT  = (size_t)NN * 4;
    const size_t SZ_SS   = (size_t)EE * 4;
    const size_t SZ_SM   = (size_t)NN * DD * 2;     //  5.12 MB
    const size_t SZ_F32  = (size_t)NN * DD * 4;     // 10.24 MB
    const size_t SZ_Q    = (size_t)NN * 512 * 2;    // 20.48 MB
    const size_t SZ_KV   = (size_t)NN * 1024;       // 20.48 MB (fp8!)
    const size_t SZ_HB   = (size_t)NN * GHC * 2;    // 20.48 MB
    const size_t WC_ELE  = 347136;
    const size_t SZ_WC   = WC_ELE * 2;
    const size_t SZ_WCB  = 16384 * 2 + 256;
    const size_t REQUIRED = SZ_OFF + 2 * SZ_CNT + SZ_SS + 2 * SZ_SM + SZ_WC + SZ_WCB
                          + SZ_Q + SZ_KV + 3 * SZ_F32 + SZ_SM + SZ_HB;

    if (ws_size < REQUIRED) return;

    char* w = (char*)d_ws;
    int* offsets = (int*)w;        w += SZ_OFF;
    int* counts  = (int*)w;        w += SZ_CNT;
    int* pos     = (int*)w;        w += SZ_CNT;
    int* sorted_src = (int*)w;     w += SZ_SS;
    unsigned short* xc   = (unsigned short*)w; w += SZ_SM;
    unsigned short* tec  = (unsigned short*)w; w += SZ_SM;
    unsigned short* wc   = (unsigned short*)w; w += SZ_WC;
    unsigned short* wcomb = (unsigned short*)w; w += 16384 * 2;
    unsigned short* bcomb = (unsigned short*)w; w += 256;
    unsigned short* qb   = (unsigned short*)w; w += SZ_Q;
    unsigned char*  kvb  = (unsigned char*)w;  w += SZ_KV;
    float*          aggb = (float*)w;          w += SZ_F32;
    float*          x1f  = (float*)w;          w += SZ_F32;
    float*          x2f  = (float*)w;          w += SZ_F32;
    unsigned short* x2b  = (unsigned short*)w; w += SZ_SM;
    unsigned short* hbuf = (unsigned short*)w; w += SZ_HB;

    unsigned short* cw = wc;
    unsigned short* qkv_w = cw; cw += 3 * 65536;
    unsigned short* qkv_b = cw; cw += 3 * 512;
    unsigned short* gs_w  = cw; cw += 16384;  unsigned short* gs_b  = cw; cw += 128;
    unsigned short* ffn_w1 = cw; cw += 65536; unsigned short* ffn_b1 = cw; cw += 512;
    unsigned short* ffn_w2 = cw; cw += 65536; unsigned short* ffn_b2 = cw; cw += 128;
    unsigned short* ln1_g = cw; cw += 128;    unsigned short* ln1_b = cw; cw += 128;
    unsigned short* ln2_g = cw; cw += 128;    unsigned short* ln2_b = cw; cw += 128;
    unsigned short* ln3_g = cw; cw += 128;    unsigned short* ln3_b = cw; cw += 128;

    const int EB = (EE + 255) / 256;
    const dim3 blk(256);
    const int MB = (NN + 63) / 64;            // 313

    WPack pack;
    const int live_idx[18] = {2,4,6, 3,5,7, 8,9, 18,19, 20,21, 22,23,24,25,26,27};
    for (int i = 0; i < 18; ++i) pack.in[i] = d_in[live_idx[i]];

    (void)hipMemsetAsync(counts, 0, SZ_CNT, stream);
    prep_kernel<<<1664 + EB, blk, 0, stream>>>((const float*)d_in[0], (const float*)d_in[1],
                                               xc, pack, wc,
                                               (const float*)d_in[14], (const float*)d_in[15],
                                               (const float*)d_in[16], (const float*)d_in[17],
                                               wcomb, bcomb, e_dst, counts);

    scan_kernel<<<1, 1024, 0, stream>>>(counts, offsets, pos, NN);
    scatter_kernel<<<EB, blk, 0, stream>>>(e_src, e_dst, pos, sorted_src, EE);

    // TransformerConv: QKV (q bf16 -> qb; k|v fp8 -> kvb), agg, fused skip+LN1
    gemm3_kernel<<<dim3(MB, 12), blk, 0, stream>>>(xc, qkv_w, qkv_b, qb, kvb,
                                                   NN, 512, 512, 0);
    agg_kernel<<<NN / 2, blk, 0, stream>>>(qb, kvb, offsets, sorted_src, aggb);
    // x1f = LN1(x_f32 + skip(xc) + agg)
    gemm_ln2_kernel<<<MB, blk, 0, stream>>>(xc, gs_w, gs_b, (const float*)d_in[0], aggb,
                                            ln1_g, ln1_b, x1f, nullptr, NN, DD);
    // x2 = LN2(x1f + TE@(WoWv)^T + bcomb) -> fp32 x2f + bf16 x2b
    gemm_ln2_kernel<<<MB, blk, 0, stream>>>(tec, wcomb, bcomb, x1f, nullptr,
                                            ln2_g, ln2_b, x2f, x2b, NN, DD);
    // FFN
    gemm3_kernel<<<dim3(MB, 4), blk, 0, stream>>>(x2b, ffn_w1, ffn_b1, hbuf, nullptr,
                                                  NN, 512, 99999, 1);
    gemm_ln2_kernel<<<MB, blk, 0, stream>>>(hbuf, ffn_w2, ffn_b2, x2f, nullptr,
                                            ln3_g, ln3_b, (float*)d_out, nullptr, NN, GHC);
}

// Round 16
// 288.734 us; speedup vs baseline: 1.0938x; 1.0208x over previous
//
#include <hip/hip_runtime.h>

// GraphTransformerLayer — MI355X
// r6=574 r7=418 r8=401 r9=384 r10=350 r11=308 r12=316 r13=314 r15=295 us.
// r15 profile: QKV gemm3 43us top, WRITE 66.7MB (>41 logical) + FETCH 31.7MB
// (>5.5 inputs) -> 8B/16B-stride partial-line kv stores cause L2 RMW.
// r16: kv row = [k 512B | v 512B] halves -> fp8 tiles write 128B/row
// contiguous (full lines); agg reads two 8B chunks (same bytes).
#define NN 20000
#define EE 160000
#define DD 128
#define GHC 512
#define INV_SQRT_HC 0.08838834764831845f  // 1/sqrt(128)

typedef __attribute__((ext_vector_type(8))) short short8;
typedef __attribute__((ext_vector_type(4))) short short4v;
typedef __attribute__((ext_vector_type(4))) float float4v;
typedef __attribute__((ext_vector_type(2))) float float2v;
typedef __attribute__((ext_vector_type(4))) unsigned uint4v;
typedef __attribute__((ext_vector_type(2))) unsigned uint2v;

__device__ inline float bf2f(unsigned short u) {
    union { unsigned u; float f; } x; x.u = ((unsigned)u) << 16; return x.f;
}
__device__ inline unsigned short f2bf(float f) {
    union { float f; unsigned u; } x; x.f = f;
    unsigned u = x.u;
    unsigned r = (u + 0x7fffu + ((u >> 16) & 1u)) >> 16;
    return (unsigned short)r;
}

// ---------------- fp8 e4m3 pack/unpack (HW cvt on gfx950; sw fallback) -----
#if defined(__has_builtin)
#if __has_builtin(__builtin_amdgcn_cvt_pk_f32_fp8) && __has_builtin(__builtin_amdgcn_cvt_pk_fp8_f32)
#define HW_FP8 1
#endif
#endif
#ifndef HW_FP8
#define HW_FP8 0
#endif

#if !HW_FP8
__device__ inline unsigned char sw_enc_fp8(float f) {
    if (!(f == f)) return 0x7f;
    unsigned s = (f < 0.f) ? 0x80u : 0u;
    float a = fabsf(f);
    if (a >= 448.f) return (unsigned char)(s | 0x7e);
    if (a < 5.96046448e-8f) return (unsigned char)s;
    int e; frexpf(a, &e);
    int E = e - 1;
    if (E < -6) E = -6;
    float q = ldexpf(rintf(ldexpf(a, 3 - E)), E - 3);
    if (q == 0.f) return (unsigned char)s;
    union { float f; unsigned u; } x; x.f = q;
    int qe = (int)((x.u >> 23) & 0xff) - 127;
    if (qe < -6) {
        unsigned mant = (unsigned)rintf(ldexpf(q, 9));
        return (unsigned char)(s | mant);
    }
    unsigned mant = (x.u >> 20) & 7;
    int ebits = qe + 7;
    if (ebits > 15) { ebits = 15; mant = 6; }
    return (unsigned char)(s | ((unsigned)ebits << 3) | mant);
}
__device__ inline float sw_dec_fp8(unsigned char u) {
    unsigned s = u >> 7, e = (u >> 3) & 15, m = u & 7;
    float v = e ? ldexpf((float)(8 + m), (int)e - 10) : ldexpf((float)m, -9);
    return s ? -v : v;
}
#endif

__device__ inline unsigned short fp8_enc2(float a, float b) {
#if HW_FP8
    int r = __builtin_amdgcn_cvt_pk_fp8_f32(a, b, 0, false);
    return (unsigned short)(r & 0xffff);
#else
    return (unsigned short)(sw_enc_fp8(a) | ((unsigned)sw_enc_fp8(b) << 8));
#endif
}
// `hi` word-sel must be an IMMEDIATE (r14 compile error) -> two variants.
__device__ inline float2v fp8_dec2_lo(unsigned w) {
#if HW_FP8
    return __builtin_amdgcn_cvt_pk_f32_fp8((int)w, false);
#else
    float2v r;
    r[0] = sw_dec_fp8((unsigned char)(w & 0xff));
    r[1] = sw_dec_fp8((unsigned char)((w >> 8) & 0xff));
    return r;
#endif
}
__device__ inline float2v fp8_dec2_hi(unsigned w) {
#if HW_FP8
    return __builtin_amdgcn_cvt_pk_f32_fp8((int)w, true);
#else
    float2v r;
    r[0] = sw_dec_fp8((unsigned char)((w >> 16) & 0xff));
    r[1] = sw_dec_fp8((unsigned char)(w >> 24));
    return r;
#endif
}

// ---------------------------------------------------------------------------
// prep: [0,1024) convert x+te -> bf16 | [1024,1600) weight pack |
//       [1600,1664) wcomb | [1664,+EB) dst histogram.  One dispatch.
// ---------------------------------------------------------------------------
struct WPack { const void* in[18]; };
__device__ __constant__ const int WSZ[18] = {
    65536, 65536, 65536, 512, 512, 512,
    16384, 128, 65536, 512, 65536, 128,
    128, 128, 128, 128, 128, 128 };

__global__ void prep_kernel(const float* __restrict__ x, const float* __restrict__ te,
                            unsigned short* __restrict__ xcout, WPack p,
                            unsigned short* __restrict__ wcout,
                            const float* __restrict__ wv, const float* __restrict__ bv,
                            const float* __restrict__ wo, const float* __restrict__ bo,
                            unsigned short* __restrict__ wcomb,
                            unsigned short* __restrict__ bcomb,
                            const int* __restrict__ e_dst, int* __restrict__ counts)
{
    const int b = blockIdx.x;
    const int tid = threadIdx.x;
    if (b < 1024) {
        const long n4half = (long)NN * DD / 4;
        short4v* out4 = reinterpret_cast<short4v*>(xcout);
        long i = (long)b * 256 + tid;
        const long stride = 1024L * 256;
        const long tot = 2 * n4half;
        for (; i < tot; i += stride) {
            const float4v* src = (i < n4half)
                ? reinterpret_cast<const float4v*>(x)
                : reinterpret_cast<const float4v*>(te) - n4half;
            float4v v = src[i];
            short4v o;
            o[0] = (short)f2bf(v[0]); o[1] = (short)f2bf(v[1]);
            o[2] = (short)f2bf(v[2]); o[3] = (short)f2bf(v[3]);
            out4[i] = o;
        }
    } else if (b < 1600) {
        const int seg = (b - 1024) >> 5;
        const int rep = (b - 1024) & 31;
        int off = 0;
#pragma unroll
        for (int s = 0; s < 18; ++s) if (s < seg) off += WSZ[s];
        const int n = WSZ[seg];
        const float* q = (const float*)p.in[seg];
        for (int i = rep * 256 + tid; i < n; i += 32 * 256)
            wcout[off + i] = f2bf(q[i]);
    } else if (b < 1664) {
        int e = (b - 1600) * 256 + tid;   // 16384 total
        int i = e >> 7, kk = e & 127;
        float s = 0.f;
        for (int j = 0; j < 128; ++j)
            s += wo[i * 128 + j] * wv[j * 128 + kk];
        wcomb[e] = f2bf(s);
        if (b == 1600 && tid < 128) {
            float t = 0.f;
            for (int j = 0; j < 128; ++j) t += wo[tid * 128 + j] * bv[j];
            bcomb[tid] = f2bf(t + bo[tid]);
        }
    } else {
        int e = (b - 1664) * 256 + tid;
        if (e < EE) {
            int d = e_dst[e];
            if (d >= 0 && d < NN) atomicAdd(&counts[d], 1);
        }
    }
}

// ---------------------------------------------------------------------------
// GEMM v3 (K=128, 128 cols/block): W slice (32KB) staged in LDS frag-major.
// cols < split  -> bf16 `out` (stride Nout).
// cols >= split -> fp8 kv buffer [M][1024B] = [k: head*128B | v: head*128B];
//                  one tile = one (which,head) = 128 CONTIGUOUS bytes/row.
// ---------------------------------------------------------------------------
__global__ __launch_bounds__(256) void gemm3_kernel(
    const unsigned short* __restrict__ A, const unsigned short* __restrict__ W,
    const unsigned short* __restrict__ bias, unsigned short* __restrict__ out,
    unsigned char* __restrict__ kvout, int M, int Nout, int split, int relu)
{
    __shared__ short8 wslab[2048];                                     // 32 KB
    __shared__ __attribute__((aligned(16))) unsigned stile[4][16][36]; // 9 KB
    const int tid  = threadIdx.x;
    const int lane = tid & 63;
    const int wid  = tid >> 6;
    const int quad = lane >> 4;
    const int l15  = lane & 15;
    const int rowbase  = blockIdx.x * 64 + wid * 16;
    const int colbase0 = blockIdx.y * 128;
    const bool isfp8 = (colbase0 >= split);
    const int kvcol = colbase0 - split;              // 0..1023 when fp8
    const int which = isfp8 ? (kvcol >> 9) : 0;      // 0=k, 1=v
    const int head  = isfp8 ? ((kvcol & 511) >> 7) : 0;

    const short8* A8 = reinterpret_cast<const short8*>(A);
    const short8* W8 = reinterpret_cast<const short8*>(W);

#pragma unroll
    for (int rep = 0; rep < 8; ++rep) {
        int f   = rep * 256 + tid;            // 0..2047
        int fl  = f & 63;
        int fi  = (f >> 6) & 3;
        int ft  = (f >> 8) & 3;
        int ftt = f >> 10;
        int wrow = colbase0 + ftt * 64 + 16 * ft + (fl & 15);
        wslab[f] = W8[(size_t)wrow * 16 + fi * 4 + (fl >> 4)];
    }

    int arow = rowbase + l15;
    if (arow >= M) arow = M - 1;
    short8 a4[4];
#pragma unroll
    for (int i = 0; i < 4; ++i) a4[i] = A8[(size_t)arow * 16 + i * 4 + quad];

    __syncthreads();

    unsigned short* fp = reinterpret_cast<unsigned short*>(&stile[wid][0][0]);

#pragma unroll
    for (int tt = 0; tt < 2; ++tt) {
        const int colbase = colbase0 + tt * 64;
        float4v acc[4];
#pragma unroll
        for (int t = 0; t < 4; ++t) acc[t] = (float4v){0.f, 0.f, 0.f, 0.f};

#pragma unroll
        for (int i = 0; i < 4; ++i) {
#pragma unroll
            for (int t = 0; t < 4; ++t) {
                short8 b = wslab[((tt * 4 + t) * 4 + i) * 64 + lane];
                acc[t] = __builtin_amdgcn_mfma_f32_16x16x32_bf16(a4[i], b, acc[t], 0, 0, 0);
            }
        }

        if (!isfp8) {
            // bf16 epilogue: shfl-pack col pairs -> dword LDS -> b128 stores
#pragma unroll
            for (int t = 0; t < 4; ++t) {
                float bv = bf2f(bias[colbase + 16 * t + l15]);
#pragma unroll
                for (int r = 0; r < 4; ++r) {
                    float vv = acc[t][r] + bv;
                    if (relu) vv = fmaxf(vv, 0.f);
                    float ov = __shfl_xor(vv, 1, 64);
                    if ((l15 & 1) == 0)
                        stile[wid][quad * 4 + r][8 * t + (l15 >> 1)] =
                            (unsigned)f2bf(vv) | ((unsigned)f2bf(ov) << 16);
                }
            }
            const int rr0 = lane >> 3;
            const int cd  = (lane & 7) * 4;
#pragma unroll
            for (int it = 0; it < 2; ++it) {
                int rr = rr0 + it * 8;
                int grow = rowbase + rr;
                if (grow < M) {
                    uint4v v = *reinterpret_cast<const uint4v*>(&stile[wid][rr][cd]);
                    *reinterpret_cast<uint4v*>(&out[(size_t)grow * Nout + colbase0 + tt * 64 + cd * 2]) = v;
                }
            }
        } else {
            // fp8: encode pairs (x256), stage row-major 64 ushorts/row (stride 72)
#pragma unroll
            for (int t = 0; t < 4; ++t) {
                float bv = bf2f(bias[colbase + 16 * t + l15]);
#pragma unroll
                for (int r = 0; r < 4; ++r) {
                    float vv = (acc[t][r] + bv) * 256.f;
                    float ov = __shfl_xor(vv, 1, 64);
                    if ((l15 & 1) == 0)
                        fp[(quad * 4 + r) * 72 + tt * 32 + ((16 * t + l15) >> 1)] =
                            fp8_enc2(vv, ov);
                }
            }
        }
    }

    if (isfp8) {
        // one store pass: 16 rows x 128B contiguous (full cache lines)
#pragma unroll
        for (int it = 0; it < 2; ++it) {
            int u = lane + it * 64;          // 0..127
            int row = u >> 3;                // 0..15
            int part = u & 7;                // 0..7 (16B each)
            int grow = rowbase + row;
            if (grow < M) {
                uint4v v = *reinterpret_cast<const uint4v*>(&fp[row * 72 + part * 8]);
                size_t ro = (size_t)grow * 1024 + (size_t)which * 512
                          + (size_t)head * 128 + (size_t)part * 16;
                *reinterpret_cast<uint4v*>(kvout + ro) = v;
            }
        }
    }
}

// ---------------------------------------------------------------------------
// GEMM + residual + LN fused, W-in-LDS chunked (Nout=128; K multiple of 128).
// ---------------------------------------------------------------------------
__global__ __launch_bounds__(256) void gemm_ln2_kernel(
    const unsigned short* __restrict__ A, const unsigned short* __restrict__ W,
    const unsigned short* __restrict__ bias,
    const float* __restrict__ residf, const float* __restrict__ c,
    const unsigned short* __restrict__ g, const unsigned short* __restrict__ beta,
    float* __restrict__ outf, unsigned short* __restrict__ outb, int M, int K)
{
    __shared__ short8 wslab[2048];                // 32 KB
    __shared__ unsigned short stile[4][16][136];
    const int tid  = threadIdx.x;
    const int lane = tid & 63;
    const int wid  = tid >> 6;
    const int quad = lane >> 4;
    const int l15  = lane & 15;
    const int rowbase = blockIdx.x * 64 + wid * 16;

    int arow = rowbase + l15;
    if (arow >= M) arow = M - 1;

    const short8* A8 = reinterpret_cast<const short8*>(A);
    const short8* W8 = reinterpret_cast<const short8*>(W);
    const int k8 = K >> 3;
    const int kchunks = K >> 7;

    float4v acc[2][4];
#pragma unroll
    for (int tt = 0; tt < 2; ++tt)
#pragma unroll
        for (int t = 0; t < 4; ++t) acc[tt][t] = (float4v){0.f, 0.f, 0.f, 0.f};

    for (int cc = 0; cc < kchunks; ++cc) {
        if (cc > 0) __syncthreads();
#pragma unroll
        for (int rep = 0; rep < 8; ++rep) {
            int f   = rep * 256 + tid;
            int fl  = f & 63;
            int fi  = (f >> 6) & 3;
            int ft  = (f >> 8) & 3;
            int ftt = f >> 10;
            int wrow = ftt * 64 + 16 * ft + (fl & 15);
            wslab[f] = W8[(size_t)wrow * k8 + cc * 16 + fi * 4 + (fl >> 4)];
        }
        short8 a4[4];
#pragma unroll
        for (int i = 0; i < 4; ++i) a4[i] = A8[(size_t)arow * k8 + cc * 16 + i * 4 + quad];
        __syncthreads();
#pragma unroll
        for (int tt = 0; tt < 2; ++tt)
#pragma unroll
            for (int i = 0; i < 4; ++i)
#pragma unroll
                for (int t = 0; t < 4; ++t) {
                    short8 b = wslab[((tt * 4 + t) * 4 + i) * 64 + lane];
                    acc[tt][t] = __builtin_amdgcn_mfma_f32_16x16x32_bf16(a4[i], b, acc[tt][t], 0, 0, 0);
                }
    }

#pragma unroll
    for (int tt = 0; tt < 2; ++tt)
#pragma unroll
        for (int t = 0; t < 4; ++t) {
            float bv = bf2f(bias[tt * 64 + 16 * t + l15]);
#pragma unroll
            for (int r = 0; r < 4; ++r)
                stile[wid][quad * 4 + r][tt * 64 + 16 * t + l15] = f2bf(acc[tt][t][r] + bv);
        }

    const int r  = lane >> 2;
    const int p  = lane & 3;
    const int grow = rowbase + r;
    const int gr = (grow < M) ? grow : M - 1;

    float v[32];
    const short8* st8 = reinterpret_cast<const short8*>(&stile[wid][r][p * 32]);
#pragma unroll
    for (int q = 0; q < 4; ++q) {
        short8 sb = st8[q];
#pragma unroll
        for (int j = 0; j < 8; ++j) v[q * 8 + j] = bf2f((unsigned short)sb[j]);
    }
    const float4v* r4 = reinterpret_cast<const float4v*>(&residf[(size_t)gr * 128 + p * 32]);
#pragma unroll
    for (int q = 0; q < 8; ++q) {
        float4v rv = r4[q];
#pragma unroll
        for (int j = 0; j < 4; ++j) v[q * 4 + j] += rv[j];
    }
    if (c) {
        const float4v* c4 = reinterpret_cast<const float4v*>(&c[(size_t)gr * 128 + p * 32]);
#pragma unroll
        for (int q = 0; q < 8; ++q) {
            float4v cv = c4[q];
#pragma unroll
            for (int j = 0; j < 4; ++j) v[q * 4 + j] += cv[j];
        }
    }
    float s = 0.f, sq = 0.f;
#pragma unroll
    for (int i = 0; i < 32; ++i) { s += v[i]; sq += v[i] * v[i]; }
    s  += __shfl_xor(s, 1, 64);  s  += __shfl_xor(s, 2, 64);
    sq += __shfl_xor(sq, 1, 64); sq += __shfl_xor(sq, 2, 64);
    float mu  = s * (1.f / 128.f);
    float var = sq * (1.f / 128.f) - mu * mu;
    float rs  = rsqrtf(fmaxf(var, 0.f) + 1e-5f);

    if (grow < M) {
        const short8* g8 = reinterpret_cast<const short8*>(&g[p * 32]);
        const short8* b8 = reinterpret_cast<const short8*>(&beta[p * 32]);
        float o[32];
#pragma unroll
        for (int q = 0; q < 4; ++q) {
            short8 gg = g8[q], bb = b8[q];
#pragma unroll
            for (int j = 0; j < 8; ++j)
                o[q * 8 + j] = (v[q * 8 + j] - mu) * rs * bf2f((unsigned short)gg[j])
                               + bf2f((unsigned short)bb[j]);
        }
        float4v* o4 = reinterpret_cast<float4v*>(outf + (size_t)grow * 128 + p * 32);
#pragma unroll
        for (int q = 0; q < 8; ++q) {
            float4v ov = {o[q * 4], o[q * 4 + 1], o[q * 4 + 2], o[q * 4 + 3]};
            o4[q] = ov;
        }
        if (outb) {
            short8* ob8 = reinterpret_cast<short8*>(outb + (size_t)grow * 128 + p * 32);
#pragma unroll
            for (int q = 0; q < 4; ++q) {
                short8 oo;
#pragma unroll
                for (int j = 0; j < 8; ++j) oo[j] = (short)f2bf(o[q * 8 + j]);
                ob8[q] = oo;
            }
        }
    }
}

// ---------------------------------------------------------------------------
// CSR scan + scatter
// ---------------------------------------------------------------------------
__global__ __launch_bounds__(1024) void scan_kernel(
    const int* __restrict__ counts, int* __restrict__ offsets, int* __restrict__ pos, int n)
{
    __shared__ int wsum[16];
    __shared__ int carry_s;
    const int tid = threadIdx.x;
    const int wid = tid >> 6, lane = tid & 63;
    int vals[20];
#pragma unroll
    for (int cI = 0; cI < 20; ++cI) {
        int i = cI * 1024 + tid;
        vals[cI] = (i < n) ? counts[i] : 0;
    }
    if (tid == 0) carry_s = 0;
    __syncthreads();
#pragma unroll
    for (int cI = 0; cI < 20; ++cI) {
        int i = cI * 1024 + tid;
        int val = vals[cI];
        int x = val;
#pragma unroll
        for (int off = 1; off < 64; off <<= 1) {
            int t = __shfl_up(x, off, 64);
            if (lane >= off) x += t;
        }
        if (lane == 63) wsum[wid] = x;
        __syncthreads();
        if (wid == 0 && lane < 16) {
            int s = wsum[lane];
#pragma unroll
            for (int off = 1; off < 16; off <<= 1) {
                int t = __shfl_up(s, off, 64);
                if (lane >= off) s += t;
            }
            wsum[lane] = s;
        }
        __syncthreads();
        int prefix = (wid > 0 ? wsum[wid - 1] : 0) + carry_s;
        int ex = prefix + x - val;
        if (i < n) { offsets[i] = ex; pos[i] = ex; }
        __syncthreads();
        if (tid == 0) carry_s += wsum[15];
        __syncthreads();
    }
    if (tid == 0) offsets[n] = carry_s;
}

__global__ void scatter_kernel(const int* __restrict__ src, const int* __restrict__ dst,
                               int* __restrict__ pos, int* __restrict__ sorted_src, int E)
{
    int e = blockIdx.x * 256 + threadIdx.x;
    if (e < E) {
        int d = dst[e];
        if (d >= 0 && d < NN) {
            int p = atomicAdd(&pos[d], 1);
            if (p >= 0 && p < E) sorted_src[p] = src[e];
        }
    }
}

// ---------------------------------------------------------------------------
// All-heads graph attention over fp8 kv: 2 waves/node (stride-2), lane-
// parallel src preload, 1-deep prefetch. kv row = [k 512B | v 512B];
// lane reads k/v 8B chunks at (head*128 + sub*8). qf folds 1/sqrt(HC)/256.
// ---------------------------------------------------------------------------
__device__ inline void agg_edge(const uint2v& kk, const uint2v& vv,
                                const float* qf, float* acc, float& ssum)
{
    float2v k01 = fp8_dec2_lo(kk[0]);
    float2v k23 = fp8_dec2_hi(kk[0]);
    float2v k45 = fp8_dec2_lo(kk[1]);
    float2v k67 = fp8_dec2_hi(kk[1]);
    float dot = qf[0] * k01[0] + qf[1] * k01[1] + qf[2] * k23[0] + qf[3] * k23[1]
              + qf[4] * k45[0] + qf[5] * k45[1] + qf[6] * k67[0] + qf[7] * k67[1];
    dot += __shfl_xor(dot, 1, 64);
    dot += __shfl_xor(dot, 2, 64);
    dot += __shfl_xor(dot, 4, 64);
    dot += __shfl_xor(dot, 8, 64);
    float pp = __expf(dot);
    ssum += pp;
    float2v v01 = fp8_dec2_lo(vv[0]);
    float2v v23 = fp8_dec2_hi(vv[0]);
    float2v v45 = fp8_dec2_lo(vv[1]);
    float2v v67 = fp8_dec2_hi(vv[1]);
    acc[0] += pp * v01[0]; acc[1] += pp * v01[1];
    acc[2] += pp * v23[0]; acc[3] += pp * v23[1];
    acc[4] += pp * v45[0]; acc[5] += pp * v45[1];
    acc[6] += pp * v67[0]; acc[7] += pp * v67[1];
}

__global__ __launch_bounds__(256) void agg_kernel(
    const unsigned short* __restrict__ q, const unsigned char* __restrict__ kvb,
    const int* __restrict__ offsets, const int* __restrict__ srcs,
    float* __restrict__ aggb)
{
    __shared__ float sacc[4][64][8];
    __shared__ float sssum[4][64];
    const int tid  = threadIdx.x;
    const int wid  = tid >> 6;
    const int lane = tid & 63;
    const int node = blockIdx.x * 2 + (wid >> 1);
    const int half = wid & 1;

    const short8* q8 = reinterpret_cast<const short8*>(q);
    const int fidx = (lane >> 4) * 16 + (lane & 15);
    const int koff = fidx * 8;            // head*128 + sub*8

    short8 qv = q8[(size_t)node * 64 + fidx];
    float qf[8];
#pragma unroll
    for (int i = 0; i < 8; ++i)
        qf[i] = bf2f((unsigned short)qv[i]) * (INV_SQRT_HC / 256.f);

    int beg = offsets[node], end = offsets[node + 1];
    if (beg < 0) beg = 0;
    if (end > EE) end = EE;
    float ssum = 0.f;
    float acc[8];
#pragma unroll
    for (int i = 0; i < 8; ++i) acc[i] = 0.f;

    const int start = beg + half;
    int nce = (end > start) ? ((end - start + 1) >> 1) : 0;
    int ncap = (nce > 64) ? 64 : nce;

    int sv = 0;
    if (lane < ncap) {
        int s = srcs[start + 2 * lane];
        if (s < 0) s = 0;
        if (s >= NN) s = NN - 1;
        sv = s;
    }
    if (ncap > 0) {
        int s0 = __shfl(sv, 0, 64);
        uint2v kc = *reinterpret_cast<const uint2v*>(kvb + (size_t)s0 * 1024 + koff);
        uint2v vc = *reinterpret_cast<const uint2v*>(kvb + (size_t)s0 * 1024 + 512 + koff);
        for (int i = 0; i < ncap; ++i) {
            uint2v kn, vn;
            if (i + 1 < ncap) {
                int sn = __shfl(sv, i + 1, 64);
                kn = *reinterpret_cast<const uint2v*>(kvb + (size_t)sn * 1024 + koff);
                vn = *reinterpret_cast<const uint2v*>(kvb + (size_t)sn * 1024 + 512 + koff);
            }
            agg_edge(kc, vc, qf, acc, ssum);
            kc = kn; vc = vn;
        }
    }
    for (int j = start + 128; j < end; j += 2) {   // pathological-degree tail
        int s = srcs[j];
        if (s < 0) s = 0;
        if (s >= NN) s = NN - 1;
        uint2v kc = *reinterpret_cast<const uint2v*>(kvb + (size_t)s * 1024 + koff);
        uint2v vc = *reinterpret_cast<const uint2v*>(kvb + (size_t)s * 1024 + 512 + koff);
        agg_edge(kc, vc, qf, acc, ssum);
    }

    // publish partials; even wave combines
#pragma unroll
    for (int i = 0; i < 8; ++i) sacc[wid][lane][i] = acc[i];
    sssum[wid][lane] = ssum;
    __syncthreads();
    if (half == 0) {
#pragma unroll
        for (int i = 0; i < 8; ++i) acc[i] += sacc[wid ^ 1][lane][i];
        ssum += sssum[wid ^ 1][lane];

        float inv = (ssum > 0.f) ? 1.f / (256.f * ssum) : 0.f;   // undo x256
#pragma unroll
        for (int i = 0; i < 8; ++i) acc[i] *= inv;
#pragma unroll
        for (int i = 0; i < 8; ++i) {
            acc[i] += __shfl_xor(acc[i], 16, 64);
            acc[i] += __shfl_xor(acc[i], 32, 64);
            acc[i] *= 0.25f;
        }
        if (lane < 16) {
            float4v* o = reinterpret_cast<float4v*>(aggb + (size_t)node * 128 + lane * 8);
            o[0] = (float4v){acc[0], acc[1], acc[2], acc[3]};
            o[1] = (float4v){acc[4], acc[5], acc[6], acc[7]};
        }
    }
}

// ---------------------------------------------------------------------------
extern "C" void kernel_launch(void* const* d_in, const int* in_sizes, int n_in,
                              void* d_out, int out_size, void* d_ws, size_t ws_size,
                              hipStream_t stream)
{
    const int* edge_index = (const int*)d_in[28];
    const int* e_src = edge_index;
    const int* e_dst = edge_index + EE;

    if (n_in < 29 || in_sizes[0] != NN * DD || in_sizes[28] != 2 * EE || out_size != NN * DD)
        return;

    const size_t SZ_OFF  = (size_t)(NN + 16) * 4;
    const size_t SZ_CNT  = (size_t)NN * 4;
    const size_t SZ_SS   = (size_t)EE * 4;
    const size_t SZ_SM   = (size_t)NN * DD * 2;     //  5.12 MB
    const size_t SZ_F32  = (size_t)NN * DD * 4;     // 10.24 MB
    const size_t SZ_Q    = (size_t)NN * 512 * 2;    // 20.48 MB
    const size_t SZ_KV   = (size_t)NN * 1024;       // 20.48 MB (fp8)
    const size_t SZ_HB   = (size_t)NN * GHC * 2;    // 20.48 MB
    const size_t WC_ELE  = 347136;
    const size_t SZ_WC   = WC_ELE * 2;
    const size_t SZ_WCB  = 16384 * 2 + 256;
    const size_t REQUIRED = SZ_OFF + 2 * SZ_CNT + SZ_SS + 2 * SZ_SM + SZ_WC + SZ_WCB
                          + SZ_Q + SZ_KV + 3 * SZ_F32 + SZ_SM + SZ_HB;

    if (ws_size < REQUIRED) return;

    char* w = (char*)d_ws;
    int* offsets = (int*)w;        w += SZ_OFF;
    int* counts  = (int*)w;        w += SZ_CNT;
    int* pos     = (int*)w;        w += SZ_CNT;
    int* sorted_src = (int*)w;     w += SZ_SS;
    unsigned short* xc   = (unsigned short*)w; w += SZ_SM;
    unsigned short* tec  = (unsigned short*)w; w += SZ_SM;
    unsigned short* wc   = (unsigned short*)w; w += SZ_WC;
    unsigned short* wcomb = (unsigned short*)w; w += 16384 * 2;
    unsigned short* bcomb = (unsigned short*)w; w += 256;
    unsigned short* qb   = (unsigned short*)w; w += SZ_Q;
    unsigned char*  kvb  = (unsigned char*)w;  w += SZ_KV;
    float*          aggb = (float*)w;          w += SZ_F32;
    float*          x1f  = (float*)w;          w += SZ_F32;
    float*          x2f  = (float*)w;          w += SZ_F32;
    unsigned short* x2b  = (unsigned short*)w; w += SZ_SM;
    unsigned short* hbuf = (unsigned short*)w; w += SZ_HB;

    unsigned short* cw = wc;
    unsigned short* qkv_w = cw; cw += 3 * 65536;
    unsigned short* qkv_b = cw; cw += 3 * 512;
    unsigned short* gs_w  = cw; cw += 16384;  unsigned short* gs_b  = cw; cw += 128;
    unsigned short* ffn_w1 = cw; cw += 65536; unsigned short* ffn_b1 = cw; cw += 512;
    unsigned short* ffn_w2 = cw; cw += 65536; unsigned short* ffn_b2 = cw; cw += 128;
    unsigned short* ln1_g = cw; cw += 128;    unsigned short* ln1_b = cw; cw += 128;
    unsigned short* ln2_g = cw; cw += 128;    unsigned short* ln2_b = cw; cw += 128;
    unsigned short* ln3_g = cw; cw += 128;    unsigned short* ln3_b = cw; cw += 128;

    const int EB = (EE + 255) / 256;
    const dim3 blk(256);
    const int MB = (NN + 63) / 64;            // 313

    WPack pack;
    const int live_idx[18] = {2,4,6, 3,5,7, 8,9, 18,19, 20,21, 22,23,24,25,26,27};
    for (int i = 0; i < 18; ++i) pack.in[i] = d_in[live_idx[i]];

    (void)hipMemsetAsync(counts, 0, SZ_CNT, stream);
    prep_kernel<<<1664 + EB, blk, 0, stream>>>((const float*)d_in[0], (const float*)d_in[1],
                                               xc, pack, wc,
                                               (const float*)d_in[14], (const float*)d_in[15],
                                               (const float*)d_in[16], (const float*)d_in[17],
                                               wcomb, bcomb, e_dst, counts);

    scan_kernel<<<1, 1024, 0, stream>>>(counts, offsets, pos, NN);
    scatter_kernel<<<EB, blk, 0, stream>>>(e_src, e_dst, pos, sorted_src, EE);

    // TransformerConv: QKV (q bf16 -> qb; k|v fp8 halves -> kvb), agg, LN1
    gemm3_kernel<<<dim3(MB, 12), blk, 0, stream>>>(xc, qkv_w, qkv_b, qb, kvb,
                                                   NN, 512, 512, 0);
    agg_kernel<<<NN / 2, blk, 0, stream>>>(qb, kvb, offsets, sorted_src, aggb);
    // x1f = LN1(x_f32 + skip(xc) + agg)
    gemm_ln2_kernel<<<MB, blk, 0, stream>>>(xc, gs_w, gs_b, (const float*)d_in[0], aggb,
                                            ln1_g, ln1_b, x1f, nullptr, NN, DD);
    // x2 = LN2(x1f + TE@(WoWv)^T + bcomb) -> fp32 x2f + bf16 x2b
    gemm_ln2_kernel<<<MB, blk, 0, stream>>>(tec, wcomb, bcomb, x1f, nullptr,
                                            ln2_g, ln2_b, x2f, x2b, NN, DD);
    // FFN
    gemm3_kernel<<<dim3(MB, 4), blk, 0, stream>>>(x2b, ffn_w1, ffn_b1, hbuf, nullptr,
                                                  NN, 512, 99999, 1);
    gemm_ln2_kernel<<<MB, blk, 0, stream>>>(hbuf, ffn_w2, ffn_b2, x2f, nullptr,
                                            ln3_g, ln3_b, (float*)d_out, nullptr, NN, GHC);
}